// Round 15
// baseline (297.412 us; speedup 1.0000x reference)
//
#include <hip/hip_runtime.h>
#include <hip/hip_bf16.h>

#define INV1P 0.9999950000374997f
#define BCAP 16384
#define CSRCAP 20480

typedef __attribute__((ext_vector_type(8))) short bfrag;   // 8 x bf16 (4 VGPR)
typedef __attribute__((ext_vector_type(4))) float f32x4;   // MFMA accumulator

static __device__ __forceinline__ unsigned bf16rne(float f) {
    unsigned u = __float_as_uint(f);
    return (u + 0x7fffu + ((u >> 16) & 1u)) >> 16;
}
static __device__ __forceinline__ float bflo(unsigned u) { return __uint_as_float(u << 16); }
static __device__ __forceinline__ float bfhi(unsigned u) { return __uint_as_float(u & 0xffff0000u); }

// ---------------- graph-structure kernels (atomic-free CSR build) ----------------

// pass A: bin edges by dst-bucket. 8192 edges/block, packed (src | dst_low<<17).
__global__ __launch_bounds__(256) void k_binA(const int* __restrict__ src, const int* __restrict__ dst,
                                              int* __restrict__ gcursor, unsigned* __restrict__ binned, int e) {
    __shared__ unsigned pk[8192];
    __shared__ unsigned char bk[8192];
    __shared__ int hist[256];
    __shared__ int base[256];
    int tid = threadIdx.x;
    hist[tid] = 0;
    __syncthreads();
    int cbase = blockIdx.x * 8192;
    int cnt = min(8192, e - cbase);
    for (int j = tid; j < cnt; j += 256) {
        int s = src[cbase + j], d = dst[cbase + j];
        unsigned b = (unsigned)d >> 9;
        pk[j] = (unsigned)s | (((unsigned)d & 511u) << 17);
        bk[j] = (unsigned char)b;
        atomicAdd(&hist[b], 1);
    }
    __syncthreads();
    int h = hist[tid];
    base[tid] = (h > 0) ? atomicAdd(&gcursor[tid], h) : 0;
    hist[tid] = 0;
    __syncthreads();
    for (int j = tid; j < cnt; j += 256) {
        unsigned b = bk[j];
        int off = atomicAdd(&hist[b], 1);
        binned[base[b] + off] = pk[j];
    }
}

// pass B: one block per bucket. Pass 1: count per-node -> dinv, rowptr/rowend
// (padded to multiple of 8, pad slots = dummy index). Pass 2: scatter to CSR.
__global__ __launch_bounds__(256) void k_binB2(const unsigned* __restrict__ binned,
                                               const int* __restrict__ gcursor,
                                               int* __restrict__ rowptr, int* __restrict__ rowend,
                                               float* __restrict__ dinv,
                                               int* __restrict__ csr_src, int n, int dummy) {
    __shared__ int cur[512];
    __shared__ int lrp[512];
    __shared__ int ssum[256];
    int b = blockIdx.x, tid = threadIdx.x;
    int nstart = b << 9;
    int nn = min(512, n - nstart);
    int cntb = gcursor[b] - b * BCAP;
    int s0 = b * BCAP, s1 = s0 + cntb;
    int cb = b * CSRCAP;
    cur[tid] = 0; cur[tid + 256] = 0;
    __syncthreads();
    for (int j = s0 + tid; j < s1; j += 256)
        atomicAdd(&cur[(binned[j] >> 17) & 511], 1);
    __syncthreads();
    int c0 = cur[2 * tid], c1 = cur[2 * tid + 1];
    int p0 = (c0 + 7) & ~7, p1 = (c1 + 7) & ~7;
    int pair = p0 + p1;
    ssum[tid] = pair;
    __syncthreads();
    for (int off = 1; off < 256; off <<= 1) {
        int t2 = (tid >= off) ? ssum[tid - off] : 0;
        __syncthreads();
        ssum[tid] += t2;
        __syncthreads();
    }
    int e0 = ssum[tid] - pair;     // exclusive (padded) for elem 2t
    int e1 = e0 + p0;
    int st0 = cb + e0, st1 = cb + e1;
    lrp[2 * tid] = st0;
    lrp[2 * tid + 1] = st1;
    if (2 * tid < nn) {
        rowptr[nstart + 2 * tid] = st0;
        rowend[nstart + 2 * tid] = st0 + p0;
        dinv[nstart + 2 * tid] = rsqrtf((float)(c0 + 1));
    }
    if (2 * tid + 1 < nn) {
        rowptr[nstart + 2 * tid + 1] = st1;
        rowend[nstart + 2 * tid + 1] = st1 + p1;
        dinv[nstart + 2 * tid + 1] = rsqrtf((float)(c1 + 1));
    }
    // pad-fill with dummy index (zero row in H)
    for (int k = c0; k < p0; k++) csr_src[st0 + k] = dummy;
    for (int k = c1; k < p1; k++) csr_src[st1 + k] = dummy;
    cur[2 * tid] = 0; cur[2 * tid + 1] = 0;
    __syncthreads();
    for (int j = s0 + tid; j < s1; j += 256) {
        unsigned p = binned[j];
        int nl = (p >> 17) & 511;
        int idx = atomicAdd(&cur[nl], 1);
        csr_src[lrp[nl] + idx] = p & 0x1ffff;
    }
}

// ---------------- dense kernels ----------------

// Build MFMA B-operand fragments from fp32 W[128][128] (row-major, W[k][n]).
// part 0 = bf16_hi(W), part 1 = bf16(W - hi)  (split for accuracy).
static __device__ __forceinline__ void prepw_body(const float* __restrict__ W, uint4* __restrict__ Bf, int blk) {
    int id = blk * 256 + threadIdx.x;          // 0..2047
    int lane = id & 63;
    int e = id >> 6;                            // 0..31
    int kk = e >> 3, c = e & 7;
    int kbase = kk * 32 + (lane >> 4) * 8;
    int col = c * 16 + (lane & 15);
    unsigned hi[8], lo[8];
    #pragma unroll
    for (int j = 0; j < 8; j++) {
        float w = W[(kbase + j) * 128 + col];
        unsigned h = bf16rne(w);
        float rh = __uint_as_float(h << 16);
        unsigned l = bf16rne(w - rh);
        hi[j] = h; lo[j] = l;
    }
    uint4 H = make_uint4(hi[0] | (hi[1] << 16), hi[2] | (hi[3] << 16),
                         hi[4] | (hi[5] << 16), hi[6] | (hi[7] << 16));
    uint4 L = make_uint4(lo[0] | (lo[1] << 16), lo[2] | (lo[3] << 16),
                         lo[4] | (lo[5] << 16), lo[6] | (lo[7] << 16));
    Bf[e * 64 + lane] = H;
    Bf[2048 + e * 64 + lane] = L;
}

// merged prep: blocks 0-23 build W frags; block 24 inits cursors + dummy rows.
__global__ __launch_bounds__(256) void k_prep(const float* __restrict__ W1, const float* __restrict__ W2,
                                              const float* __restrict__ W3,
                                              uint4* __restrict__ Bf1, uint4* __restrict__ Bf2,
                                              uint4* __restrict__ Bf3,
                                              int* __restrict__ gcursor,
                                              unsigned* __restrict__ bufA, unsigned* __restrict__ bufB, int n) {
    int b = blockIdx.x;
    if (b < 8)       prepw_body(W1, Bf1, b);
    else if (b < 16) prepw_body(W2, Bf2, b - 8);
    else if (b < 24) prepw_body(W3, Bf3, b - 16);
    else {
        int t = threadIdx.x;
        gcursor[t] = t * BCAP;
        if (t < 64)  bufA[(size_t)n * 64 + t] = 0;
        else if (t < 128) bufB[(size_t)n * 64 + (t - 64)] = 0;
    }
}

// common MFMA GEMM body (128 rows/block): a[4] fragments already loaded.
// Y'[n,128](bf16) = (A @ (Whi+Wlo)) * dinv[row]. 512 threads = 8 waves.
static __device__ __forceinline__ void gemm_body(unsigned* __restrict__ Y, const float* __restrict__ dinv,
                                                 int nrows, int rowbase, bfrag* a, uint4* bs) {
    int tid = threadIdx.x;
    int w = tid >> 6, lane = tid & 63;
    __syncthreads();   // bs staged
    f32x4 acc[8];
    #pragma unroll
    for (int c = 0; c < 8; c++) acc[c] = (f32x4){0.f, 0.f, 0.f, 0.f};
    #pragma unroll
    for (int kk = 0; kk < 4; kk++) {
        #pragma unroll
        for (int c = 0; c < 8; c++) {
            bfrag bh = *(const bfrag*)&bs[(kk * 8 + c) * 64 + lane];
            bfrag bl = *(const bfrag*)&bs[2048 + (kk * 8 + c) * 64 + lane];
            acc[c] = __builtin_amdgcn_mfma_f32_16x16x32_bf16(a[kk], bh, acc[c], 0, 0, 0);
            acc[c] = __builtin_amdgcn_mfma_f32_16x16x32_bf16(a[kk], bl, acc[c], 0, 0, 0);
        }
    }
    int rb = rowbase + w * 16 + (lane >> 4) * 4;
    float dv[4];
    #pragma unroll
    for (int r = 0; r < 4; r++) dv[r] = dinv[min(rb + r, nrows - 1)];
    __syncthreads();
    char* epib = (char*)bs;
    ushort* epi = (ushort*)(epib + w * 4352);
    #pragma unroll
    for (int c = 0; c < 8; c++) {
        #pragma unroll
        for (int r = 0; r < 4; r++) {
            int rr = (lane >> 4) * 4 + r;
            epi[rr * 136 + c * 16 + (lane & 15)] = (ushort)bf16rne(acc[c][r] * dv[r]);
        }
    }
    __syncthreads();
    #pragma unroll
    for (int i = 0; i < 4; i++) {
        int id = tid + i * 512;
        int rr = id >> 4, q = id & 15;
        int grow = rowbase + rr;
        if (grow < nrows) {
            uint4 v = *(const uint4*)(epib + (rr >> 4) * 4352 + (rr & 15) * 272 + q * 16);
            ((uint4*)Y)[(size_t)grow * 16 + q] = v;
        }
    }
}

// layer-1: reads fp32 X, converts to bf16 fragments in-register.
__global__ __launch_bounds__(512) void k_gemm_mfma_f32(const float* __restrict__ X,
                                                       const uint4* __restrict__ Bfr,
                                                       unsigned* __restrict__ Y, const float* __restrict__ dinv,
                                                       int nrows) {
    __shared__ uint4 bs[4096];
    int tid = threadIdx.x;
    int w = tid >> 6, lane = tid & 63;
    int rowbase = blockIdx.x * 128;
    #pragma unroll
    for (int i = 0; i < 8; i++) bs[tid + i * 512] = Bfr[tid + i * 512];
    int row = rowbase + w * 16 + (lane & 15);
    int rowc = min(row, nrows - 1);
    const float4* X4 = (const float4*)X;
    bfrag a[4];
    #pragma unroll
    for (int kk = 0; kk < 4; kk++) {
        float4 f0 = X4[(size_t)rowc * 32 + kk * 8 + (lane >> 4) * 2];
        float4 f1 = X4[(size_t)rowc * 32 + kk * 8 + (lane >> 4) * 2 + 1];
        uint4 av = make_uint4(bf16rne(f0.x) | (bf16rne(f0.y) << 16),
                              bf16rne(f0.z) | (bf16rne(f0.w) << 16),
                              bf16rne(f1.x) | (bf16rne(f1.y) << 16),
                              bf16rne(f1.z) | (bf16rne(f1.w) << 16));
        a[kk] = *(const bfrag*)&av;
    }
    gemm_body(Y, dinv, nrows, rowbase, a, bs);
}

// aggregate inner body: accumulate padded CSR gathers into acc[8] (fp32).
static __device__ __forceinline__ void agg_body(const uint4* __restrict__ H4, int nodec, int l,
                                                const int* __restrict__ rowptr, const int* __restrict__ rowend,
                                                const int* __restrict__ csr_src, float* acc) {
    {
        uint4 hv = H4[(size_t)nodec * 16 + l];   // Y'[dst] (self term, pre-scaled)
        acc[0] = bflo(hv.x); acc[1] = bfhi(hv.x);
        acc[2] = bflo(hv.y); acc[3] = bfhi(hv.y);
        acc[4] = bflo(hv.z); acc[5] = bfhi(hv.z);
        acc[6] = bflo(hv.w); acc[7] = bfhi(hv.w);
    }
    int s = rowptr[nodec], e = rowend[nodec];
    const int4* csr4 = (const int4*)csr_src;   // rowptr multiples of 8 -> 32B aligned
    int4 ia, ib;
    if (s < e) {
        ia = csr4[(s >> 2)];
        ib = csr4[(s >> 2) + 1];
    }
    for (int j = s; j < e; j += 8) {
        uint4 vv[8];
        vv[0] = H4[(size_t)ia.x * 16 + l];
        vv[1] = H4[(size_t)ia.y * 16 + l];
        vv[2] = H4[(size_t)ia.z * 16 + l];
        vv[3] = H4[(size_t)ia.w * 16 + l];
        vv[4] = H4[(size_t)ib.x * 16 + l];
        vv[5] = H4[(size_t)ib.y * 16 + l];
        vv[6] = H4[(size_t)ib.z * 16 + l];
        vv[7] = H4[(size_t)ib.w * 16 + l];
        int jn = j + 8;
        if (jn < e) {
            ia = csr4[(jn >> 2)];
            ib = csr4[(jn >> 2) + 1];
        }
        #pragma unroll
        for (int q = 0; q < 8; q++) {
            acc[0] += bflo(vv[q].x); acc[1] += bfhi(vv[q].x);
            acc[2] += bflo(vv[q].y); acc[3] += bfhi(vv[q].y);
            acc[4] += bflo(vv[q].z); acc[5] += bfhi(vv[q].z);
            acc[6] += bflo(vv[q].w); acc[7] += bfhi(vv[q].w);
        }
    }
}

// BN+ReLU epilogue on acc[8] -> r[8]
static __device__ __forceinline__ void bn_relu(const float* acc, float dn, int l,
                                               const float* __restrict__ bias, const float* __restrict__ gamma,
                                               const float* __restrict__ beta, float* r) {
    float4 bi0 = ((const float4*)bias)[l * 2],  bi1 = ((const float4*)bias)[l * 2 + 1];
    float4 ga0 = ((const float4*)gamma)[l * 2], ga1 = ((const float4*)gamma)[l * 2 + 1];
    float4 be0 = ((const float4*)beta)[l * 2],  be1 = ((const float4*)beta)[l * 2 + 1];
    float g[8] = {ga0.x, ga0.y, ga0.z, ga0.w, ga1.x, ga1.y, ga1.z, ga1.w};
    float bb[8] = {bi0.x, bi0.y, bi0.z, bi0.w, bi1.x, bi1.y, bi1.z, bi1.w};
    float bt[8] = {be0.x, be0.y, be0.z, be0.w, be1.x, be1.y, be1.z, be1.w};
    #pragma unroll
    for (int i = 0; i < 8; i++) {
        float t = g[i] * INV1P;
        r[i] = fmaxf(fmaf(t * dn, acc[i], fmaf(t, bb[i], bt[i])), 0.f);
    }
}

// FUSED: aggregate layer i (64 nodes/block) -> h rows in LDS -> GEMM i+1 -> Y'_{i+1}.
// Single LDS buffer (17 KB): Phase B holds all accumulators in registers and
// overwrites hs in place after a sync (r13: two buffers = 34.8 KB capped
// occupancy at 33% and cost +18 us/dispatch).
__global__ __launch_bounds__(256) void k_agg_gemm(const uint4* __restrict__ H4,
                                                  const int* __restrict__ rowptr, const int* __restrict__ rowend,
                                                  const int* __restrict__ csr_src,
                                                  const float* __restrict__ dinv,
                                                  const float* __restrict__ bias, const float* __restrict__ gamma,
                                                  const float* __restrict__ beta,
                                                  const uint4* __restrict__ Bfr,
                                                  unsigned* __restrict__ Yn, int nnodes) {
    __shared__ ushort hs[64 * 136];
    int tid = threadIdx.x;
    int nl = tid >> 4;          // 0..15
    int l = tid & 15;
    int base = blockIdx.x * 64;

    // Phase A: aggregate 64 nodes (4 iterations of 16)
    for (int it = 0; it < 4; it++) {
        int node = base + it * 16 + nl;
        int nodec = min(node, nnodes - 1);
        float acc[8], r[8];
        agg_body(H4, nodec, l, rowptr, rowend, csr_src, acc);
        bn_relu(acc, dinv[nodec], l, bias, gamma, beta, r);
        uint4 o;
        o.x = bf16rne(r[0]) | (bf16rne(r[1]) << 16);
        o.y = bf16rne(r[2]) | (bf16rne(r[3]) << 16);
        o.z = bf16rne(r[4]) | (bf16rne(r[5]) << 16);
        o.w = bf16rne(r[6]) | (bf16rne(r[7]) << 16);
        *(uint4*)&hs[(it * 16 + nl) * 136 + l * 8] = o;
    }
    __syncthreads();

    // Phase B: GEMM. wave w -> col tiles {2w, 2w+1}, 4 row tiles; defer writes.
    int w = tid >> 6, lane = tid & 63;
    int c0 = 2 * w, c1 = 2 * w + 1;
    f32x4 ac0[4], ac1[4];
    #pragma unroll
    for (int t = 0; t < 4; t++) {
        bfrag a[4];
        #pragma unroll
        for (int kk = 0; kk < 4; kk++)
            a[kk] = *(const bfrag*)&hs[(t * 16 + (lane & 15)) * 136 + (lane >> 4) * 8 + kk * 32];
        ac0[t] = (f32x4){0.f, 0.f, 0.f, 0.f};
        ac1[t] = (f32x4){0.f, 0.f, 0.f, 0.f};
        #pragma unroll
        for (int kk = 0; kk < 4; kk++) {
            bfrag bh0 = *(const bfrag*)&Bfr[(kk * 8 + c0) * 64 + lane];
            bfrag bl0 = *(const bfrag*)&Bfr[2048 + (kk * 8 + c0) * 64 + lane];
            bfrag bh1 = *(const bfrag*)&Bfr[(kk * 8 + c1) * 64 + lane];
            bfrag bl1 = *(const bfrag*)&Bfr[2048 + (kk * 8 + c1) * 64 + lane];
            ac0[t] = __builtin_amdgcn_mfma_f32_16x16x32_bf16(a[kk], bh0, ac0[t], 0, 0, 0);
            ac0[t] = __builtin_amdgcn_mfma_f32_16x16x32_bf16(a[kk], bl0, ac0[t], 0, 0, 0);
            ac1[t] = __builtin_amdgcn_mfma_f32_16x16x32_bf16(a[kk], bh1, ac1[t], 0, 0, 0);
            ac1[t] = __builtin_amdgcn_mfma_f32_16x16x32_bf16(a[kk], bl1, ac1[t], 0, 0, 0);
        }
    }
    __syncthreads();   // all hs reads done; reuse hs for output
    #pragma unroll
    for (int t = 0; t < 4; t++) {
        #pragma unroll
        for (int r = 0; r < 4; r++) {
            int rowt = (lane >> 4) * 4 + r;
            float dv = dinv[min(base + t * 16 + rowt, nnodes - 1)];
            hs[(t * 16 + rowt) * 136 + c0 * 16 + (lane & 15)] = (ushort)bf16rne(ac0[t][r] * dv);
            hs[(t * 16 + rowt) * 136 + c1 * 16 + (lane & 15)] = (ushort)bf16rne(ac1[t][r] * dv);
        }
    }
    __syncthreads();
    #pragma unroll
    for (int i = 0; i < 4; i++) {
        int id = tid + i * 256;       // 0..1023
        int row = id >> 4, q = id & 15;
        int grow = base + row;
        if (grow < nnodes)
            ((uint4*)Yn)[(size_t)grow * 16 + q] = *(const uint4*)&hs[row * 136 + q * 8];
    }
}

// final aggregate (layer 3): writes h3 bf16. 16 lanes/node, 16 nodes per 256-thr block.
__global__ __launch_bounds__(256) void k_aggregate(const uint4* __restrict__ H4, const int* __restrict__ rowptr,
                                                   const int* __restrict__ rowend,
                                                   const int* __restrict__ csr_src,
                                                   const float* __restrict__ dinv,
                                                   const float* __restrict__ bias, const float* __restrict__ gamma,
                                                   const float* __restrict__ beta,
                                                   uint4* __restrict__ out4, int nnodes) {
    int tid = blockIdx.x * 256 + threadIdx.x;
    int node = tid >> 4;
    int l = tid & 15;
    if (node >= nnodes) return;
    float acc[8], r[8];
    agg_body(H4, node, l, rowptr, rowend, csr_src, acc);
    bn_relu(acc, dinv[node], l, bias, gamma, beta, r);
    uint4 o;
    o.x = bf16rne(r[0]) | (bf16rne(r[1]) << 16);
    o.y = bf16rne(r[2]) | (bf16rne(r[3]) << 16);
    o.z = bf16rne(r[4]) | (bf16rne(r[5]) << 16);
    o.w = bf16rne(r[6]) | (bf16rne(r[7]) << 16);
    out4[(size_t)node * 16 + l] = o;
}

// pooled sums from bf16 H: 64 consecutive nodes per 64-thread block; batch sorted.
__global__ __launch_bounds__(64) void k_pool(const unsigned* __restrict__ Hf, const int* __restrict__ batch,
                                             float* __restrict__ pooled, float* __restrict__ cnt, int nnodes) {
    int t = threadIdx.x;
    int base = blockIdx.x * 64;
    if (base >= nnodes) return;
    int end = min(base + 64, nnodes);
    float ax = 0.f, ay = 0.f; int run = 0;
    int cur = batch[base];
    for (int i = base; i < end; i++) {
        int bg = batch[i];
        if (bg != cur) {
            atomicAdd(&pooled[(size_t)cur * 128 + 2 * t], ax);
            atomicAdd(&pooled[(size_t)cur * 128 + 2 * t + 1], ay);
            if (t == 0) atomicAdd(&cnt[cur], (float)run);
            ax = 0.f; ay = 0.f; run = 0; cur = bg;
        }
        unsigned u = Hf[(size_t)i * 64 + t];
        ax += bflo(u);
        ay += bfhi(u);
        run++;
    }
    atomicAdd(&pooled[(size_t)cur * 128 + 2 * t], ax);
    atomicAdd(&pooled[(size_t)cur * 128 + 2 * t + 1], ay);
    if (t == 0) atomicAdd(&cnt[cur], (float)run);
}

// classifier: one 64-thread block per graph. 128 -> 64 (relu) -> 10
__global__ __launch_bounds__(64) void k_classifier(const float* __restrict__ pooled, const float* __restrict__ cnt,
                                                   const float* __restrict__ Wc1, const float* __restrict__ bc1,
                                                   const float* __restrict__ Wc2, const float* __restrict__ bc2,
                                                   float* __restrict__ outp, int ngraphs) {
    __shared__ float p[128];
    __shared__ float z[64];
    int g = blockIdx.x;
    int tid = threadIdx.x;
    float inv = 1.0f / fmaxf(cnt[g], 1.0f);
    p[tid]      = pooled[(size_t)g * 128 + tid] * inv;
    p[tid + 64] = pooled[(size_t)g * 128 + 64 + tid] * inv;
    __syncthreads();
    float a = bc1[tid];
    #pragma unroll 8
    for (int k = 0; k < 128; k++) a += p[k] * Wc1[k * 64 + tid];
    z[tid] = fmaxf(a, 0.f);
    __syncthreads();
    if (tid < 10) {
        float o = bc2[tid];
        #pragma unroll 8
        for (int j = 0; j < 64; j++) o += z[j] * Wc2[j * 10 + tid];
        outp[(size_t)g * 10 + tid] = o;
    }
}

// ---------------- launch ----------------

static inline size_t align16(size_t v) { return (v + 15) & ~(size_t)15; }

extern "C" void kernel_launch(void* const* d_in, const int* in_sizes, int n_in,
                              void* d_out, int out_size, void* d_ws, size_t ws_size,
                              hipStream_t stream) {
    const float* x      = (const float*)d_in[0];
    const int*   ei     = (const int*)d_in[1];
    const int*   batch  = (const int*)d_in[2];
    const float* W1 = (const float*)d_in[3];  const float* b1 = (const float*)d_in[4];
    const float* W2 = (const float*)d_in[5];  const float* b2 = (const float*)d_in[6];
    const float* W3 = (const float*)d_in[7];  const float* b3 = (const float*)d_in[8];
    const float* g1 = (const float*)d_in[9];  const float* be1 = (const float*)d_in[10];
    const float* g2 = (const float*)d_in[11]; const float* be2 = (const float*)d_in[12];
    const float* g3 = (const float*)d_in[13]; const float* be3 = (const float*)d_in[14];
    const float* Wc1 = (const float*)d_in[15]; const float* bc1 = (const float*)d_in[16];
    const float* Wc2 = (const float*)d_in[17]; const float* bc2 = (const float*)d_in[18];

    const int N = in_sizes[0] / 128;
    const int E = in_sizes[1] / 2;
    const int G = out_size / 10;
    const int* srcp = ei;
    const int* dstp = ei + E;
    const int NB = (N + 511) >> 9;   // dst buckets of 512 nodes

    // workspace layout (16B-aligned slots); bufA/bufB have +1 zero dummy row
    char* ws = (char*)d_ws;
    size_t off = 0;
    unsigned* bufA = (unsigned*)(ws + off); off = align16(off + (size_t)(N + 1) * 64 * 4);
    unsigned* bufB = (unsigned*)(ws + off); off = align16(off + (size_t)(N + 1) * 64 * 4);
    uint4* Bfr1 = (uint4*)(ws + off); off = align16(off + 4096 * 16);
    uint4* Bfr2 = (uint4*)(ws + off); off = align16(off + 4096 * 16);
    uint4* Bfr3 = (uint4*)(ws + off); off = align16(off + 4096 * 16);
    int*   csr_src = (int*)(ws + off);  off = align16(off + (size_t)NB * CSRCAP * 4);
    unsigned* binned = (unsigned*)(ws + off); off = align16(off + (size_t)NB * BCAP * 4);
    float* dinv   = (float*)(ws + off); off = align16(off + (size_t)N * 4);
    int*   rowptr = (int*)(ws + off);   off = align16(off + (size_t)N * 4);
    int*   rowend = (int*)(ws + off);   off = align16(off + (size_t)N * 4);
    int*   gcursor = (int*)(ws + off);  off = align16(off + 256 * 4);
    float* pooled = (float*)(ws + off); off = align16(off + (size_t)G * 128 * 4);
    float* cnt    = (float*)(ws + off); off = align16(off + (size_t)G * 4);
    (void)ws_size;

    int gE8 = (E + 8191) / 8192;

    // weight frags + cursor init + dummy-row zeroing (one launch)
    k_prep<<<25, 256, 0, stream>>>(W1, W2, W3, Bfr1, Bfr2, Bfr3, gcursor, bufA, bufB, N);

    // graph structure: atomic-free CSR build (over-allocated buckets, padded rows)
    k_binA<<<gE8, 256, 0, stream>>>(srcp, dstp, gcursor, binned, E);
    k_binB2<<<NB, 256, 0, stream>>>(binned, gcursor, rowptr, rowend, dinv, csr_src, N, N);

    int gGemm = (N + 127) / 128;
    int gFuse = (N + 63) / 64;
    int gAgg  = (N * 16 + 255) / 256;

    // layer 1 GEMM (fp32 input, in-register convert) -> Y1' (bufA)
    k_gemm_mfma_f32<<<gGemm, 512, 0, stream>>>(x, Bfr1, bufA, dinv, N);
    // fused layer 1 aggregate + layer 2 GEMM -> Y2' (bufB)
    k_agg_gemm<<<gFuse, 256, 0, stream>>>((const uint4*)bufA, rowptr, rowend, csr_src, dinv,
                                          b1, g1, be1, Bfr2, bufB, N);
    // fused layer 2 aggregate + layer 3 GEMM -> Y3' (bufA)
    k_agg_gemm<<<gFuse, 256, 0, stream>>>((const uint4*)bufB, rowptr, rowend, csr_src, dinv,
                                          b2, g2, be2, Bfr3, bufA, N);
    // final aggregate -> h3 (bufB)
    k_aggregate<<<gAgg, 256, 0, stream>>>((const uint4*)bufA, rowptr, rowend, csr_src, dinv,
                                          b3, g3, be3, (uint4*)bufB, N);

    // pooling
    hipMemsetAsync(pooled, 0, ((size_t)G * 128 + G) * 4, stream);
    int gPool = (N + 63) / 64;
    k_pool<<<gPool, 64, 0, stream>>>(bufB, batch, pooled, cnt, N);

    // classifier
    k_classifier<<<G, 64, 0, stream>>>(pooled, cnt, Wc1, bc1, Wc2, bc2, (float*)d_out, G);
}

// Round 16
// 296.431 us; speedup vs baseline: 1.0033x; 1.0033x over previous
//
#include <hip/hip_runtime.h>
#include <hip/hip_bf16.h>

#define INV1P 0.9999950000374997f
#define BCAP 16384
#define CSRCAP 20480

typedef __attribute__((ext_vector_type(8))) short bfrag;   // 8 x bf16 (4 VGPR)
typedef __attribute__((ext_vector_type(4))) float f32x4;   // MFMA accumulator

static __device__ __forceinline__ unsigned bf16rne(float f) {
    unsigned u = __float_as_uint(f);
    return (u + 0x7fffu + ((u >> 16) & 1u)) >> 16;
}
static __device__ __forceinline__ float bflo(unsigned u) { return __uint_as_float(u << 16); }
static __device__ __forceinline__ float bfhi(unsigned u) { return __uint_as_float(u & 0xffff0000u); }

// ---------------- graph-structure kernels (atomic-free CSR build) ----------------

// pass A: bin edges by dst-bucket. 8192 edges/block, packed (src | dst_low<<17).
__global__ __launch_bounds__(256) void k_binA(const int* __restrict__ src, const int* __restrict__ dst,
                                              int* __restrict__ gcursor, unsigned* __restrict__ binned, int e) {
    __shared__ unsigned pk[8192];
    __shared__ unsigned char bk[8192];
    __shared__ int hist[256];
    __shared__ int base[256];
    int tid = threadIdx.x;
    hist[tid] = 0;
    __syncthreads();
    int cbase = blockIdx.x * 8192;
    int cnt = min(8192, e - cbase);
    for (int j = tid; j < cnt; j += 256) {
        int s = src[cbase + j], d = dst[cbase + j];
        unsigned b = (unsigned)d >> 9;
        pk[j] = (unsigned)s | (((unsigned)d & 511u) << 17);
        bk[j] = (unsigned char)b;
        atomicAdd(&hist[b], 1);
    }
    __syncthreads();
    int h = hist[tid];
    base[tid] = (h > 0) ? atomicAdd(&gcursor[tid], h) : 0;
    hist[tid] = 0;
    __syncthreads();
    for (int j = tid; j < cnt; j += 256) {
        unsigned b = bk[j];
        int off = atomicAdd(&hist[b], 1);
        binned[base[b] + off] = pk[j];
    }
}

// pass B: one block per bucket. Pass 1: count per-node -> dinv, rowptr/rowend
// (padded to multiple of 8, pad slots = dummy index). Pass 2: scatter to CSR.
__global__ __launch_bounds__(256) void k_binB2(const unsigned* __restrict__ binned,
                                               const int* __restrict__ gcursor,
                                               int* __restrict__ rowptr, int* __restrict__ rowend,
                                               float* __restrict__ dinv,
                                               int* __restrict__ csr_src, int n, int dummy) {
    __shared__ int cur[512];
    __shared__ int lrp[512];
    __shared__ int ssum[256];
    int b = blockIdx.x, tid = threadIdx.x;
    int nstart = b << 9;
    int nn = min(512, n - nstart);
    int cntb = gcursor[b] - b * BCAP;
    int s0 = b * BCAP, s1 = s0 + cntb;
    int cb = b * CSRCAP;
    cur[tid] = 0; cur[tid + 256] = 0;
    __syncthreads();
    for (int j = s0 + tid; j < s1; j += 256)
        atomicAdd(&cur[(binned[j] >> 17) & 511], 1);
    __syncthreads();
    int c0 = cur[2 * tid], c1 = cur[2 * tid + 1];
    int p0 = (c0 + 7) & ~7, p1 = (c1 + 7) & ~7;
    int pair = p0 + p1;
    ssum[tid] = pair;
    __syncthreads();
    for (int off = 1; off < 256; off <<= 1) {
        int t2 = (tid >= off) ? ssum[tid - off] : 0;
        __syncthreads();
        ssum[tid] += t2;
        __syncthreads();
    }
    int e0 = ssum[tid] - pair;     // exclusive (padded) for elem 2t
    int e1 = e0 + p0;
    int st0 = cb + e0, st1 = cb + e1;
    lrp[2 * tid] = st0;
    lrp[2 * tid + 1] = st1;
    if (2 * tid < nn) {
        rowptr[nstart + 2 * tid] = st0;
        rowend[nstart + 2 * tid] = st0 + p0;
        dinv[nstart + 2 * tid] = rsqrtf((float)(c0 + 1));
    }
    if (2 * tid + 1 < nn) {
        rowptr[nstart + 2 * tid + 1] = st1;
        rowend[nstart + 2 * tid + 1] = st1 + p1;
        dinv[nstart + 2 * tid + 1] = rsqrtf((float)(c1 + 1));
    }
    // pad-fill with dummy index (zero row in H)
    for (int k = c0; k < p0; k++) csr_src[st0 + k] = dummy;
    for (int k = c1; k < p1; k++) csr_src[st1 + k] = dummy;
    cur[2 * tid] = 0; cur[2 * tid + 1] = 0;
    __syncthreads();
    for (int j = s0 + tid; j < s1; j += 256) {
        unsigned p = binned[j];
        int nl = (p >> 17) & 511;
        int idx = atomicAdd(&cur[nl], 1);
        csr_src[lrp[nl] + idx] = p & 0x1ffff;
    }
}

// ---------------- dense kernels ----------------

// Build MFMA B-operand fragments from fp32 W[128][128] (row-major, W[k][n]).
// part 0 = bf16_hi(W), part 1 = bf16(W - hi)  (split for accuracy).
static __device__ __forceinline__ void prepw_body(const float* __restrict__ W, uint4* __restrict__ Bf, int blk) {
    int id = blk * 256 + threadIdx.x;          // 0..2047
    int lane = id & 63;
    int e = id >> 6;                            // 0..31
    int kk = e >> 3, c = e & 7;
    int kbase = kk * 32 + (lane >> 4) * 8;
    int col = c * 16 + (lane & 15);
    unsigned hi[8], lo[8];
    #pragma unroll
    for (int j = 0; j < 8; j++) {
        float w = W[(kbase + j) * 128 + col];
        unsigned h = bf16rne(w);
        float rh = __uint_as_float(h << 16);
        unsigned l = bf16rne(w - rh);
        hi[j] = h; lo[j] = l;
    }
    uint4 H = make_uint4(hi[0] | (hi[1] << 16), hi[2] | (hi[3] << 16),
                         hi[4] | (hi[5] << 16), hi[6] | (hi[7] << 16));
    uint4 L = make_uint4(lo[0] | (lo[1] << 16), lo[2] | (lo[3] << 16),
                         lo[4] | (lo[5] << 16), lo[6] | (lo[7] << 16));
    Bf[e * 64 + lane] = H;
    Bf[2048 + e * 64 + lane] = L;
}

// merged prep: blocks 0-23 build W frags; block 24 inits cursors + dummy rows.
__global__ __launch_bounds__(256) void k_prep(const float* __restrict__ W1, const float* __restrict__ W2,
                                              const float* __restrict__ W3,
                                              uint4* __restrict__ Bf1, uint4* __restrict__ Bf2,
                                              uint4* __restrict__ Bf3,
                                              int* __restrict__ gcursor,
                                              unsigned* __restrict__ bufA, unsigned* __restrict__ bufB, int n) {
    int b = blockIdx.x;
    if (b < 8)       prepw_body(W1, Bf1, b);
    else if (b < 16) prepw_body(W2, Bf2, b - 8);
    else if (b < 24) prepw_body(W3, Bf3, b - 16);
    else {
        int t = threadIdx.x;
        gcursor[t] = t * BCAP;
        if (t < 64)  bufA[(size_t)n * 64 + t] = 0;
        else if (t < 128) bufB[(size_t)n * 64 + (t - 64)] = 0;
    }
}

// common MFMA GEMM body (128 rows/block): a[4] fragments already loaded.
// Y'[n,128](bf16) = (A @ (Whi+Wlo)) * dinv[row]. 512 threads = 8 waves.
static __device__ __forceinline__ void gemm_body(unsigned* __restrict__ Y, const float* __restrict__ dinv,
                                                 int nrows, int rowbase, bfrag* a, uint4* bs) {
    int tid = threadIdx.x;
    int w = tid >> 6, lane = tid & 63;
    __syncthreads();   // bs staged
    f32x4 acc[8];
    #pragma unroll
    for (int c = 0; c < 8; c++) acc[c] = (f32x4){0.f, 0.f, 0.f, 0.f};
    #pragma unroll
    for (int kk = 0; kk < 4; kk++) {
        #pragma unroll
        for (int c = 0; c < 8; c++) {
            bfrag bh = *(const bfrag*)&bs[(kk * 8 + c) * 64 + lane];
            bfrag bl = *(const bfrag*)&bs[2048 + (kk * 8 + c) * 64 + lane];
            acc[c] = __builtin_amdgcn_mfma_f32_16x16x32_bf16(a[kk], bh, acc[c], 0, 0, 0);
            acc[c] = __builtin_amdgcn_mfma_f32_16x16x32_bf16(a[kk], bl, acc[c], 0, 0, 0);
        }
    }
    int rb = rowbase + w * 16 + (lane >> 4) * 4;
    float dv[4];
    #pragma unroll
    for (int r = 0; r < 4; r++) dv[r] = dinv[min(rb + r, nrows - 1)];
    __syncthreads();
    char* epib = (char*)bs;
    ushort* epi = (ushort*)(epib + w * 4352);
    #pragma unroll
    for (int c = 0; c < 8; c++) {
        #pragma unroll
        for (int r = 0; r < 4; r++) {
            int rr = (lane >> 4) * 4 + r;
            epi[rr * 136 + c * 16 + (lane & 15)] = (ushort)bf16rne(acc[c][r] * dv[r]);
        }
    }
    __syncthreads();
    #pragma unroll
    for (int i = 0; i < 4; i++) {
        int id = tid + i * 512;
        int rr = id >> 4, q = id & 15;
        int grow = rowbase + rr;
        if (grow < nrows) {
            uint4 v = *(const uint4*)(epib + (rr >> 4) * 4352 + (rr & 15) * 272 + q * 16);
            ((uint4*)Y)[(size_t)grow * 16 + q] = v;
        }
    }
}

// layer-1: reads fp32 X, converts to bf16 fragments in-register.
__global__ __launch_bounds__(512) void k_gemm_mfma_f32(const float* __restrict__ X,
                                                       const uint4* __restrict__ Bfr,
                                                       unsigned* __restrict__ Y, const float* __restrict__ dinv,
                                                       int nrows) {
    __shared__ uint4 bs[4096];
    int tid = threadIdx.x;
    int w = tid >> 6, lane = tid & 63;
    int rowbase = blockIdx.x * 128;
    #pragma unroll
    for (int i = 0; i < 8; i++) bs[tid + i * 512] = Bfr[tid + i * 512];
    int row = rowbase + w * 16 + (lane & 15);
    int rowc = min(row, nrows - 1);
    const float4* X4 = (const float4*)X;
    bfrag a[4];
    #pragma unroll
    for (int kk = 0; kk < 4; kk++) {
        float4 f0 = X4[(size_t)rowc * 32 + kk * 8 + (lane >> 4) * 2];
        float4 f1 = X4[(size_t)rowc * 32 + kk * 8 + (lane >> 4) * 2 + 1];
        uint4 av = make_uint4(bf16rne(f0.x) | (bf16rne(f0.y) << 16),
                              bf16rne(f0.z) | (bf16rne(f0.w) << 16),
                              bf16rne(f1.x) | (bf16rne(f1.y) << 16),
                              bf16rne(f1.z) | (bf16rne(f1.w) << 16));
        a[kk] = *(const bfrag*)&av;
    }
    gemm_body(Y, dinv, nrows, rowbase, a, bs);
}

// aggregate inner body: accumulate padded CSR gathers into acc[8] (fp32).
static __device__ __forceinline__ void agg_body(const uint4* __restrict__ H4, int nodec, int l,
                                                const int* __restrict__ rowptr, const int* __restrict__ rowend,
                                                const int* __restrict__ csr_src, float* acc) {
    {
        uint4 hv = H4[(size_t)nodec * 16 + l];   // Y'[dst] (self term, pre-scaled)
        acc[0] = bflo(hv.x); acc[1] = bfhi(hv.x);
        acc[2] = bflo(hv.y); acc[3] = bfhi(hv.y);
        acc[4] = bflo(hv.z); acc[5] = bfhi(hv.z);
        acc[6] = bflo(hv.w); acc[7] = bfhi(hv.w);
    }
    int s = rowptr[nodec], e = rowend[nodec];
    const int4* csr4 = (const int4*)csr_src;   // rowptr multiples of 8 -> 32B aligned
    int4 ia, ib;
    if (s < e) {
        ia = csr4[(s >> 2)];
        ib = csr4[(s >> 2) + 1];
    }
    for (int j = s; j < e; j += 8) {
        uint4 vv[8];
        vv[0] = H4[(size_t)ia.x * 16 + l];
        vv[1] = H4[(size_t)ia.y * 16 + l];
        vv[2] = H4[(size_t)ia.z * 16 + l];
        vv[3] = H4[(size_t)ia.w * 16 + l];
        vv[4] = H4[(size_t)ib.x * 16 + l];
        vv[5] = H4[(size_t)ib.y * 16 + l];
        vv[6] = H4[(size_t)ib.z * 16 + l];
        vv[7] = H4[(size_t)ib.w * 16 + l];
        int jn = j + 8;
        if (jn < e) {
            ia = csr4[(jn >> 2)];
            ib = csr4[(jn >> 2) + 1];
        }
        #pragma unroll
        for (int q = 0; q < 8; q++) {
            acc[0] += bflo(vv[q].x); acc[1] += bfhi(vv[q].x);
            acc[2] += bflo(vv[q].y); acc[3] += bfhi(vv[q].y);
            acc[4] += bflo(vv[q].z); acc[5] += bfhi(vv[q].z);
            acc[6] += bflo(vv[q].w); acc[7] += bfhi(vv[q].w);
        }
    }
}

// BN+ReLU epilogue on acc[8] -> r[8]
static __device__ __forceinline__ void bn_relu(const float* acc, float dn, int l,
                                               const float* __restrict__ bias, const float* __restrict__ gamma,
                                               const float* __restrict__ beta, float* r) {
    float4 bi0 = ((const float4*)bias)[l * 2],  bi1 = ((const float4*)bias)[l * 2 + 1];
    float4 ga0 = ((const float4*)gamma)[l * 2], ga1 = ((const float4*)gamma)[l * 2 + 1];
    float4 be0 = ((const float4*)beta)[l * 2],  be1 = ((const float4*)beta)[l * 2 + 1];
    float g[8] = {ga0.x, ga0.y, ga0.z, ga0.w, ga1.x, ga1.y, ga1.z, ga1.w};
    float bb[8] = {bi0.x, bi0.y, bi0.z, bi0.w, bi1.x, bi1.y, bi1.z, bi1.w};
    float bt[8] = {be0.x, be0.y, be0.z, be0.w, be1.x, be1.y, be1.z, be1.w};
    #pragma unroll
    for (int i = 0; i < 8; i++) {
        float t = g[i] * INV1P;
        r[i] = fmaxf(fmaf(t * dn, acc[i], fmaf(t, bb[i], bt[i])), 0.f);
    }
}

// FUSED: aggregate layer i (64 nodes/block) -> h rows in LDS -> GEMM i+1 -> Y'_{i+1}.
// Single LDS buffer (17 KB): Phase B holds all accumulators in registers and
// overwrites hs in place after a sync (r13: two buffers = 34.8 KB capped
// occupancy at 33% and cost +18 us/dispatch).
__global__ __launch_bounds__(256) void k_agg_gemm(const uint4* __restrict__ H4,
                                                  const int* __restrict__ rowptr, const int* __restrict__ rowend,
                                                  const int* __restrict__ csr_src,
                                                  const float* __restrict__ dinv,
                                                  const float* __restrict__ bias, const float* __restrict__ gamma,
                                                  const float* __restrict__ beta,
                                                  const uint4* __restrict__ Bfr,
                                                  unsigned* __restrict__ Yn, int nnodes) {
    __shared__ ushort hs[64 * 136];
    int tid = threadIdx.x;
    int nl = tid >> 4;          // 0..15
    int l = tid & 15;
    int base = blockIdx.x * 64;

    // Phase A: aggregate 64 nodes (4 iterations of 16)
    for (int it = 0; it < 4; it++) {
        int node = base + it * 16 + nl;
        int nodec = min(node, nnodes - 1);
        float acc[8], r[8];
        agg_body(H4, nodec, l, rowptr, rowend, csr_src, acc);
        bn_relu(acc, dinv[nodec], l, bias, gamma, beta, r);
        uint4 o;
        o.x = bf16rne(r[0]) | (bf16rne(r[1]) << 16);
        o.y = bf16rne(r[2]) | (bf16rne(r[3]) << 16);
        o.z = bf16rne(r[4]) | (bf16rne(r[5]) << 16);
        o.w = bf16rne(r[6]) | (bf16rne(r[7]) << 16);
        *(uint4*)&hs[(it * 16 + nl) * 136 + l * 8] = o;
    }
    __syncthreads();

    // Phase B: GEMM. wave w -> col tiles {2w, 2w+1}, 4 row tiles; defer writes.
    int w = tid >> 6, lane = tid & 63;
    int c0 = 2 * w, c1 = 2 * w + 1;
    f32x4 ac0[4], ac1[4];
    #pragma unroll
    for (int t = 0; t < 4; t++) {
        bfrag a[4];
        #pragma unroll
        for (int kk = 0; kk < 4; kk++)
            a[kk] = *(const bfrag*)&hs[(t * 16 + (lane & 15)) * 136 + (lane >> 4) * 8 + kk * 32];
        ac0[t] = (f32x4){0.f, 0.f, 0.f, 0.f};
        ac1[t] = (f32x4){0.f, 0.f, 0.f, 0.f};
        #pragma unroll
        for (int kk = 0; kk < 4; kk++) {
            bfrag bh0 = *(const bfrag*)&Bfr[(kk * 8 + c0) * 64 + lane];
            bfrag bl0 = *(const bfrag*)&Bfr[2048 + (kk * 8 + c0) * 64 + lane];
            bfrag bh1 = *(const bfrag*)&Bfr[(kk * 8 + c1) * 64 + lane];
            bfrag bl1 = *(const bfrag*)&Bfr[2048 + (kk * 8 + c1) * 64 + lane];
            ac0[t] = __builtin_amdgcn_mfma_f32_16x16x32_bf16(a[kk], bh0, ac0[t], 0, 0, 0);
            ac0[t] = __builtin_amdgcn_mfma_f32_16x16x32_bf16(a[kk], bl0, ac0[t], 0, 0, 0);
            ac1[t] = __builtin_amdgcn_mfma_f32_16x16x32_bf16(a[kk], bh1, ac1[t], 0, 0, 0);
            ac1[t] = __builtin_amdgcn_mfma_f32_16x16x32_bf16(a[kk], bl1, ac1[t], 0, 0, 0);
        }
    }
    __syncthreads();   // all hs reads done; reuse hs for output
    #pragma unroll
    for (int t = 0; t < 4; t++) {
        #pragma unroll
        for (int r = 0; r < 4; r++) {
            int rowt = (lane >> 4) * 4 + r;
            float dv = dinv[min(base + t * 16 + rowt, nnodes - 1)];
            hs[(t * 16 + rowt) * 136 + c0 * 16 + (lane & 15)] = (ushort)bf16rne(ac0[t][r] * dv);
            hs[(t * 16 + rowt) * 136 + c1 * 16 + (lane & 15)] = (ushort)bf16rne(ac1[t][r] * dv);
        }
    }
    __syncthreads();
    #pragma unroll
    for (int i = 0; i < 4; i++) {
        int id = tid + i * 256;       // 0..1023
        int row = id >> 4, q = id & 15;
        int grow = base + row;
        if (grow < nnodes)
            ((uint4*)Yn)[(size_t)grow * 16 + q] = *(const uint4*)&hs[row * 136 + q * 8];
    }
}

// final aggregate (layer 3): writes h3 bf16. 16 lanes/node, 16 nodes per 256-thr block.
__global__ __launch_bounds__(256) void k_aggregate(const uint4* __restrict__ H4, const int* __restrict__ rowptr,
                                                   const int* __restrict__ rowend,
                                                   const int* __restrict__ csr_src,
                                                   const float* __restrict__ dinv,
                                                   const float* __restrict__ bias, const float* __restrict__ gamma,
                                                   const float* __restrict__ beta,
                                                   uint4* __restrict__ out4, int nnodes) {
    int tid = blockIdx.x * 256 + threadIdx.x;
    int node = tid >> 4;
    int l = tid & 15;
    if (node >= nnodes) return;
    float acc[8], r[8];
    agg_body(H4, node, l, rowptr, rowend, csr_src, acc);
    bn_relu(acc, dinv[node], l, bias, gamma, beta, r);
    uint4 o;
    o.x = bf16rne(r[0]) | (bf16rne(r[1]) << 16);
    o.y = bf16rne(r[2]) | (bf16rne(r[3]) << 16);
    o.z = bf16rne(r[4]) | (bf16rne(r[5]) << 16);
    o.w = bf16rne(r[6]) | (bf16rne(r[7]) << 16);
    out4[(size_t)node * 16 + l] = o;
}

// pooled sums from bf16 H: 64 consecutive nodes per 64-thread block; batch sorted.
__global__ __launch_bounds__(64) void k_pool(const unsigned* __restrict__ Hf, const int* __restrict__ batch,
                                             float* __restrict__ pooled, float* __restrict__ cnt, int nnodes) {
    int t = threadIdx.x;
    int base = blockIdx.x * 64;
    if (base >= nnodes) return;
    int end = min(base + 64, nnodes);
    float ax = 0.f, ay = 0.f; int run = 0;
    int cur = batch[base];
    for (int i = base; i < end; i++) {
        int bg = batch[i];
        if (bg != cur) {
            atomicAdd(&pooled[(size_t)cur * 128 + 2 * t], ax);
            atomicAdd(&pooled[(size_t)cur * 128 + 2 * t + 1], ay);
            if (t == 0) atomicAdd(&cnt[cur], (float)run);
            ax = 0.f; ay = 0.f; run = 0; cur = bg;
        }
        unsigned u = Hf[(size_t)i * 64 + t];
        ax += bflo(u);
        ay += bfhi(u);
        run++;
    }
    atomicAdd(&pooled[(size_t)cur * 128 + 2 * t], ax);
    atomicAdd(&pooled[(size_t)cur * 128 + 2 * t + 1], ay);
    if (t == 0) atomicAdd(&cnt[cur], (float)run);
}

// classifier: one 64-thread block per graph. 128 -> 64 (relu) -> 10
__global__ __launch_bounds__(64) void k_classifier(const float* __restrict__ pooled, const float* __restrict__ cnt,
                                                   const float* __restrict__ Wc1, const float* __restrict__ bc1,
                                                   const float* __restrict__ Wc2, const float* __restrict__ bc2,
                                                   float* __restrict__ outp, int ngraphs) {
    __shared__ float p[128];
    __shared__ float z[64];
    int g = blockIdx.x;
    int tid = threadIdx.x;
    float inv = 1.0f / fmaxf(cnt[g], 1.0f);
    p[tid]      = pooled[(size_t)g * 128 + tid] * inv;
    p[tid + 64] = pooled[(size_t)g * 128 + 64 + tid] * inv;
    __syncthreads();
    float a = bc1[tid];
    #pragma unroll 8
    for (int k = 0; k < 128; k++) a += p[k] * Wc1[k * 64 + tid];
    z[tid] = fmaxf(a, 0.f);
    __syncthreads();
    if (tid < 10) {
        float o = bc2[tid];
        #pragma unroll 8
        for (int j = 0; j < 64; j++) o += z[j] * Wc2[j * 10 + tid];
        outp[(size_t)g * 10 + tid] = o;
    }
}

// ---------------- launch ----------------

static inline size_t align16(size_t v) { return (v + 15) & ~(size_t)15; }

extern "C" void kernel_launch(void* const* d_in, const int* in_sizes, int n_in,
                              void* d_out, int out_size, void* d_ws, size_t ws_size,
                              hipStream_t stream) {
    const float* x      = (const float*)d_in[0];
    const int*   ei     = (const int*)d_in[1];
    const int*   batch  = (const int*)d_in[2];
    const float* W1 = (const float*)d_in[3];  const float* b1 = (const float*)d_in[4];
    const float* W2 = (const float*)d_in[5];  const float* b2 = (const float*)d_in[6];
    const float* W3 = (const float*)d_in[7];  const float* b3 = (const float*)d_in[8];
    const float* g1 = (const float*)d_in[9];  const float* be1 = (const float*)d_in[10];
    const float* g2 = (const float*)d_in[11]; const float* be2 = (const float*)d_in[12];
    const float* g3 = (const float*)d_in[13]; const float* be3 = (const float*)d_in[14];
    const float* Wc1 = (const float*)d_in[15]; const float* bc1 = (const float*)d_in[16];
    const float* Wc2 = (const float*)d_in[17]; const float* bc2 = (const float*)d_in[18];

    const int N = in_sizes[0] / 128;
    const int E = in_sizes[1] / 2;
    const int G = out_size / 10;
    const int* srcp = ei;
    const int* dstp = ei + E;
    const int NB = (N + 511) >> 9;   // dst buckets of 512 nodes

    // workspace layout (16B-aligned slots); bufA/bufB have +1 zero dummy row
    char* ws = (char*)d_ws;
    size_t off = 0;
    unsigned* bufA = (unsigned*)(ws + off); off = align16(off + (size_t)(N + 1) * 64 * 4);
    unsigned* bufB = (unsigned*)(ws + off); off = align16(off + (size_t)(N + 1) * 64 * 4);
    uint4* Bfr1 = (uint4*)(ws + off); off = align16(off + 4096 * 16);
    uint4* Bfr2 = (uint4*)(ws + off); off = align16(off + 4096 * 16);
    uint4* Bfr3 = (uint4*)(ws + off); off = align16(off + 4096 * 16);
    int*   csr_src = (int*)(ws + off);  off = align16(off + (size_t)NB * CSRCAP * 4);
    unsigned* binned = (unsigned*)(ws + off); off = align16(off + (size_t)NB * BCAP * 4);
    float* dinv   = (float*)(ws + off); off = align16(off + (size_t)N * 4);
    int*   rowptr = (int*)(ws + off);   off = align16(off + (size_t)N * 4);
    int*   rowend = (int*)(ws + off);   off = align16(off + (size_t)N * 4);
    int*   gcursor = (int*)(ws + off);  off = align16(off + 256 * 4);
    float* pooled = (float*)(ws + off); off = align16(off + (size_t)G * 128 * 4);
    float* cnt    = (float*)(ws + off); off = align16(off + (size_t)G * 4);
    (void)ws_size;

    int gE8 = (E + 8191) / 8192;

    // weight frags + cursor init + dummy-row zeroing (one launch)
    k_prep<<<25, 256, 0, stream>>>(W1, W2, W3, Bfr1, Bfr2, Bfr3, gcursor, bufA, bufB, N);

    // graph structure: atomic-free CSR build (over-allocated buckets, padded rows)
    k_binA<<<gE8, 256, 0, stream>>>(srcp, dstp, gcursor, binned, E);
    k_binB2<<<NB, 256, 0, stream>>>(binned, gcursor, rowptr, rowend, dinv, csr_src, N, N);

    int gGemm = (N + 127) / 128;
    int gFuse = (N + 63) / 64;
    int gAgg  = (N * 16 + 255) / 256;

    // layer 1 GEMM (fp32 input, in-register convert) -> Y1' (bufA)
    k_gemm_mfma_f32<<<gGemm, 512, 0, stream>>>(x, Bfr1, bufA, dinv, N);
    // fused layer 1 aggregate + layer 2 GEMM -> Y2' (bufB)
    k_agg_gemm<<<gFuse, 256, 0, stream>>>((const uint4*)bufA, rowptr, rowend, csr_src, dinv,
                                          b1, g1, be1, Bfr2, bufB, N);
    // fused layer 2 aggregate + layer 3 GEMM -> Y3' (bufA)
    k_agg_gemm<<<gFuse, 256, 0, stream>>>((const uint4*)bufB, rowptr, rowend, csr_src, dinv,
                                          b2, g2, be2, Bfr3, bufA, N);
    // final aggregate -> h3 (bufB)
    k_aggregate<<<gAgg, 256, 0, stream>>>((const uint4*)bufA, rowptr, rowend, csr_src, dinv,
                                          b3, g3, be3, (uint4*)bufB, N);

    // pooling
    hipMemsetAsync(pooled, 0, ((size_t)G * 128 + G) * 4, stream);
    int gPool = (N + 63) / 64;
    k_pool<<<gPool, 64, 0, stream>>>(bufB, batch, pooled, cnt, N);

    // classifier
    k_classifier<<<G, 64, 0, stream>>>(pooled, cnt, Wc1, bc1, Wc2, bc2, (float*)d_out, G);
}

// Round 17
// 295.988 us; speedup vs baseline: 1.0048x; 1.0015x over previous
//
#include <hip/hip_runtime.h>
#include <hip/hip_bf16.h>

#define INV1P 0.9999950000374997f
#define BCAP 16384
#define CSRCAP 20480

typedef __attribute__((ext_vector_type(8))) short bfrag;   // 8 x bf16 (4 VGPR)
typedef __attribute__((ext_vector_type(4))) float f32x4;   // MFMA accumulator

static __device__ __forceinline__ unsigned bf16rne(float f) {
    unsigned u = __float_as_uint(f);
    return (u + 0x7fffu + ((u >> 16) & 1u)) >> 16;
}
static __device__ __forceinline__ float bflo(unsigned u) { return __uint_as_float(u << 16); }
static __device__ __forceinline__ float bfhi(unsigned u) { return __uint_as_float(u & 0xffff0000u); }

// ---------------- graph-structure kernels (atomic-free CSR build) ----------------

// pass A: bin edges by dst-bucket. 8192 edges/block, packed (src | dst_low<<17).
__global__ __launch_bounds__(256) void k_binA(const int* __restrict__ src, const int* __restrict__ dst,
                                              int* __restrict__ gcursor, unsigned* __restrict__ binned, int e) {
    __shared__ unsigned pk[8192];
    __shared__ unsigned char bk[8192];
    __shared__ int hist[256];
    __shared__ int base[256];
    int tid = threadIdx.x;
    hist[tid] = 0;
    __syncthreads();
    int cbase = blockIdx.x * 8192;
    int cnt = min(8192, e - cbase);
    for (int j = tid; j < cnt; j += 256) {
        int s = src[cbase + j], d = dst[cbase + j];
        unsigned b = (unsigned)d >> 9;
        pk[j] = (unsigned)s | (((unsigned)d & 511u) << 17);
        bk[j] = (unsigned char)b;
        atomicAdd(&hist[b], 1);
    }
    __syncthreads();
    int h = hist[tid];
    base[tid] = (h > 0) ? atomicAdd(&gcursor[tid], h) : 0;
    hist[tid] = 0;
    __syncthreads();
    for (int j = tid; j < cnt; j += 256) {
        unsigned b = bk[j];
        int off = atomicAdd(&hist[b], 1);
        binned[base[b] + off] = pk[j];
    }
}

// pass B: one block per bucket. Pass 1: count per-node -> dinv, rowptr/rowend
// (padded to multiple of 8, pad slots = dummy index). Pass 2: scatter to CSR.
__global__ __launch_bounds__(256) void k_binB2(const unsigned* __restrict__ binned,
                                               const int* __restrict__ gcursor,
                                               int* __restrict__ rowptr, int* __restrict__ rowend,
                                               float* __restrict__ dinv,
                                               int* __restrict__ csr_src, int n, int dummy) {
    __shared__ int cur[512];
    __shared__ int lrp[512];
    __shared__ int ssum[256];
    int b = blockIdx.x, tid = threadIdx.x;
    int nstart = b << 9;
    int nn = min(512, n - nstart);
    int cntb = gcursor[b] - b * BCAP;
    int s0 = b * BCAP, s1 = s0 + cntb;
    int cb = b * CSRCAP;
    cur[tid] = 0; cur[tid + 256] = 0;
    __syncthreads();
    for (int j = s0 + tid; j < s1; j += 256)
        atomicAdd(&cur[(binned[j] >> 17) & 511], 1);
    __syncthreads();
    int c0 = cur[2 * tid], c1 = cur[2 * tid + 1];
    int p0 = (c0 + 7) & ~7, p1 = (c1 + 7) & ~7;
    int pair = p0 + p1;
    ssum[tid] = pair;
    __syncthreads();
    for (int off = 1; off < 256; off <<= 1) {
        int t2 = (tid >= off) ? ssum[tid - off] : 0;
        __syncthreads();
        ssum[tid] += t2;
        __syncthreads();
    }
    int e0 = ssum[tid] - pair;     // exclusive (padded) for elem 2t
    int e1 = e0 + p0;
    int st0 = cb + e0, st1 = cb + e1;
    lrp[2 * tid] = st0;
    lrp[2 * tid + 1] = st1;
    if (2 * tid < nn) {
        rowptr[nstart + 2 * tid] = st0;
        rowend[nstart + 2 * tid] = st0 + p0;
        dinv[nstart + 2 * tid] = rsqrtf((float)(c0 + 1));
    }
    if (2 * tid + 1 < nn) {
        rowptr[nstart + 2 * tid + 1] = st1;
        rowend[nstart + 2 * tid + 1] = st1 + p1;
        dinv[nstart + 2 * tid + 1] = rsqrtf((float)(c1 + 1));
    }
    // pad-fill with dummy index (zero row in H)
    for (int k = c0; k < p0; k++) csr_src[st0 + k] = dummy;
    for (int k = c1; k < p1; k++) csr_src[st1 + k] = dummy;
    cur[2 * tid] = 0; cur[2 * tid + 1] = 0;
    __syncthreads();
    for (int j = s0 + tid; j < s1; j += 256) {
        unsigned p = binned[j];
        int nl = (p >> 17) & 511;
        int idx = atomicAdd(&cur[nl], 1);
        csr_src[lrp[nl] + idx] = p & 0x1ffff;
    }
}

// ---------------- dense kernels ----------------

// Build MFMA B-operand fragments from fp32 W[128][128] (row-major, W[k][n]).
// part 0 = bf16_hi(W), part 1 = bf16(W - hi)  (split for accuracy).
static __device__ __forceinline__ void prepw_body(const float* __restrict__ W, uint4* __restrict__ Bf, int blk) {
    int id = blk * 256 + threadIdx.x;          // 0..2047
    int lane = id & 63;
    int e = id >> 6;                            // 0..31
    int kk = e >> 3, c = e & 7;
    int kbase = kk * 32 + (lane >> 4) * 8;
    int col = c * 16 + (lane & 15);
    unsigned hi[8], lo[8];
    #pragma unroll
    for (int j = 0; j < 8; j++) {
        float w = W[(kbase + j) * 128 + col];
        unsigned h = bf16rne(w);
        float rh = __uint_as_float(h << 16);
        unsigned l = bf16rne(w - rh);
        hi[j] = h; lo[j] = l;
    }
    uint4 H = make_uint4(hi[0] | (hi[1] << 16), hi[2] | (hi[3] << 16),
                         hi[4] | (hi[5] << 16), hi[6] | (hi[7] << 16));
    uint4 L = make_uint4(lo[0] | (lo[1] << 16), lo[2] | (lo[3] << 16),
                         lo[4] | (lo[5] << 16), lo[6] | (lo[7] << 16));
    Bf[e * 64 + lane] = H;
    Bf[2048 + e * 64 + lane] = L;
}

// merged prep: blocks 0-23 build W frags; block 24 inits cursors + dummy rows.
__global__ __launch_bounds__(256) void k_prep(const float* __restrict__ W1, const float* __restrict__ W2,
                                              const float* __restrict__ W3,
                                              uint4* __restrict__ Bf1, uint4* __restrict__ Bf2,
                                              uint4* __restrict__ Bf3,
                                              int* __restrict__ gcursor,
                                              unsigned* __restrict__ bufA, unsigned* __restrict__ bufB, int n) {
    int b = blockIdx.x;
    if (b < 8)       prepw_body(W1, Bf1, b);
    else if (b < 16) prepw_body(W2, Bf2, b - 8);
    else if (b < 24) prepw_body(W3, Bf3, b - 16);
    else {
        int t = threadIdx.x;
        gcursor[t] = t * BCAP;
        if (t < 64)  bufA[(size_t)n * 64 + t] = 0;
        else if (t < 128) bufB[(size_t)n * 64 + (t - 64)] = 0;
    }
}

// common MFMA GEMM body (128 rows/block): a[4] fragments already loaded.
// Y'[n,128](bf16) = (A @ (Whi+Wlo)) * dinv[row]. 512 threads = 8 waves.
static __device__ __forceinline__ void gemm_body(unsigned* __restrict__ Y, const float* __restrict__ dinv,
                                                 int nrows, int rowbase, bfrag* a, uint4* bs) {
    int tid = threadIdx.x;
    int w = tid >> 6, lane = tid & 63;
    __syncthreads();   // bs staged
    f32x4 acc[8];
    #pragma unroll
    for (int c = 0; c < 8; c++) acc[c] = (f32x4){0.f, 0.f, 0.f, 0.f};
    #pragma unroll
    for (int kk = 0; kk < 4; kk++) {
        #pragma unroll
        for (int c = 0; c < 8; c++) {
            bfrag bh = *(const bfrag*)&bs[(kk * 8 + c) * 64 + lane];
            bfrag bl = *(const bfrag*)&bs[2048 + (kk * 8 + c) * 64 + lane];
            acc[c] = __builtin_amdgcn_mfma_f32_16x16x32_bf16(a[kk], bh, acc[c], 0, 0, 0);
            acc[c] = __builtin_amdgcn_mfma_f32_16x16x32_bf16(a[kk], bl, acc[c], 0, 0, 0);
        }
    }
    int rb = rowbase + w * 16 + (lane >> 4) * 4;
    float dv[4];
    #pragma unroll
    for (int r = 0; r < 4; r++) dv[r] = dinv[min(rb + r, nrows - 1)];
    __syncthreads();
    char* epib = (char*)bs;
    ushort* epi = (ushort*)(epib + w * 4352);
    #pragma unroll
    for (int c = 0; c < 8; c++) {
        #pragma unroll
        for (int r = 0; r < 4; r++) {
            int rr = (lane >> 4) * 4 + r;
            epi[rr * 136 + c * 16 + (lane & 15)] = (ushort)bf16rne(acc[c][r] * dv[r]);
        }
    }
    __syncthreads();
    #pragma unroll
    for (int i = 0; i < 4; i++) {
        int id = tid + i * 512;
        int rr = id >> 4, q = id & 15;
        int grow = rowbase + rr;
        if (grow < nrows) {
            uint4 v = *(const uint4*)(epib + (rr >> 4) * 4352 + (rr & 15) * 272 + q * 16);
            ((uint4*)Y)[(size_t)grow * 16 + q] = v;
        }
    }
}

// layer-1: reads fp32 X, converts to bf16 fragments in-register.
__global__ __launch_bounds__(512) void k_gemm_mfma_f32(const float* __restrict__ X,
                                                       const uint4* __restrict__ Bfr,
                                                       unsigned* __restrict__ Y, const float* __restrict__ dinv,
                                                       int nrows) {
    __shared__ uint4 bs[4096];
    int tid = threadIdx.x;
    int w = tid >> 6, lane = tid & 63;
    int rowbase = blockIdx.x * 128;
    #pragma unroll
    for (int i = 0; i < 8; i++) bs[tid + i * 512] = Bfr[tid + i * 512];
    int row = rowbase + w * 16 + (lane & 15);
    int rowc = min(row, nrows - 1);
    const float4* X4 = (const float4*)X;
    bfrag a[4];
    #pragma unroll
    for (int kk = 0; kk < 4; kk++) {
        float4 f0 = X4[(size_t)rowc * 32 + kk * 8 + (lane >> 4) * 2];
        float4 f1 = X4[(size_t)rowc * 32 + kk * 8 + (lane >> 4) * 2 + 1];
        uint4 av = make_uint4(bf16rne(f0.x) | (bf16rne(f0.y) << 16),
                              bf16rne(f0.z) | (bf16rne(f0.w) << 16),
                              bf16rne(f1.x) | (bf16rne(f1.y) << 16),
                              bf16rne(f1.z) | (bf16rne(f1.w) << 16));
        a[kk] = *(const bfrag*)&av;
    }
    gemm_body(Y, dinv, nrows, rowbase, a, bs);
}

// aggregate inner body: accumulate padded CSR gathers into acc[8] (fp32).
static __device__ __forceinline__ void agg_body(const uint4* __restrict__ H4, int nodec, int l,
                                                const int* __restrict__ rowptr, const int* __restrict__ rowend,
                                                const int* __restrict__ csr_src, float* acc) {
    {
        uint4 hv = H4[(size_t)nodec * 16 + l];   // Y'[dst] (self term, pre-scaled)
        acc[0] = bflo(hv.x); acc[1] = bfhi(hv.x);
        acc[2] = bflo(hv.y); acc[3] = bfhi(hv.y);
        acc[4] = bflo(hv.z); acc[5] = bfhi(hv.z);
        acc[6] = bflo(hv.w); acc[7] = bfhi(hv.w);
    }
    int s = rowptr[nodec], e = rowend[nodec];
    const int4* csr4 = (const int4*)csr_src;   // rowptr multiples of 8 -> 32B aligned
    int4 ia, ib;
    if (s < e) {
        ia = csr4[(s >> 2)];
        ib = csr4[(s >> 2) + 1];
    }
    for (int j = s; j < e; j += 8) {
        uint4 vv[8];
        vv[0] = H4[(size_t)ia.x * 16 + l];
        vv[1] = H4[(size_t)ia.y * 16 + l];
        vv[2] = H4[(size_t)ia.z * 16 + l];
        vv[3] = H4[(size_t)ia.w * 16 + l];
        vv[4] = H4[(size_t)ib.x * 16 + l];
        vv[5] = H4[(size_t)ib.y * 16 + l];
        vv[6] = H4[(size_t)ib.z * 16 + l];
        vv[7] = H4[(size_t)ib.w * 16 + l];
        int jn = j + 8;
        if (jn < e) {
            ia = csr4[(jn >> 2)];
            ib = csr4[(jn >> 2) + 1];
        }
        #pragma unroll
        for (int q = 0; q < 8; q++) {
            acc[0] += bflo(vv[q].x); acc[1] += bfhi(vv[q].x);
            acc[2] += bflo(vv[q].y); acc[3] += bfhi(vv[q].y);
            acc[4] += bflo(vv[q].z); acc[5] += bfhi(vv[q].z);
            acc[6] += bflo(vv[q].w); acc[7] += bfhi(vv[q].w);
        }
    }
}

// BN+ReLU epilogue on acc[8] -> r[8]
static __device__ __forceinline__ void bn_relu(const float* acc, float dn, int l,
                                               const float* __restrict__ bias, const float* __restrict__ gamma,
                                               const float* __restrict__ beta, float* r) {
    float4 bi0 = ((const float4*)bias)[l * 2],  bi1 = ((const float4*)bias)[l * 2 + 1];
    float4 ga0 = ((const float4*)gamma)[l * 2], ga1 = ((const float4*)gamma)[l * 2 + 1];
    float4 be0 = ((const float4*)beta)[l * 2],  be1 = ((const float4*)beta)[l * 2 + 1];
    float g[8] = {ga0.x, ga0.y, ga0.z, ga0.w, ga1.x, ga1.y, ga1.z, ga1.w};
    float bb[8] = {bi0.x, bi0.y, bi0.z, bi0.w, bi1.x, bi1.y, bi1.z, bi1.w};
    float bt[8] = {be0.x, be0.y, be0.z, be0.w, be1.x, be1.y, be1.z, be1.w};
    #pragma unroll
    for (int i = 0; i < 8; i++) {
        float t = g[i] * INV1P;
        r[i] = fmaxf(fmaf(t * dn, acc[i], fmaf(t, bb[i], bt[i])), 0.f);
    }
}

// FUSED: aggregate layer i (64 nodes/block) -> h rows in LDS -> GEMM i+1 -> Y'_{i+1}.
// Single LDS buffer (17 KB): Phase B holds all accumulators in registers and
// overwrites hs in place after a sync (r13: two buffers = 34.8 KB capped
// occupancy at 33% and cost +18 us/dispatch).
__global__ __launch_bounds__(256) void k_agg_gemm(const uint4* __restrict__ H4,
                                                  const int* __restrict__ rowptr, const int* __restrict__ rowend,
                                                  const int* __restrict__ csr_src,
                                                  const float* __restrict__ dinv,
                                                  const float* __restrict__ bias, const float* __restrict__ gamma,
                                                  const float* __restrict__ beta,
                                                  const uint4* __restrict__ Bfr,
                                                  unsigned* __restrict__ Yn, int nnodes) {
    __shared__ ushort hs[64 * 136];
    int tid = threadIdx.x;
    int nl = tid >> 4;          // 0..15
    int l = tid & 15;
    int base = blockIdx.x * 64;

    // Phase A: aggregate 64 nodes (4 iterations of 16)
    for (int it = 0; it < 4; it++) {
        int node = base + it * 16 + nl;
        int nodec = min(node, nnodes - 1);
        float acc[8], r[8];
        agg_body(H4, nodec, l, rowptr, rowend, csr_src, acc);
        bn_relu(acc, dinv[nodec], l, bias, gamma, beta, r);
        uint4 o;
        o.x = bf16rne(r[0]) | (bf16rne(r[1]) << 16);
        o.y = bf16rne(r[2]) | (bf16rne(r[3]) << 16);
        o.z = bf16rne(r[4]) | (bf16rne(r[5]) << 16);
        o.w = bf16rne(r[6]) | (bf16rne(r[7]) << 16);
        *(uint4*)&hs[(it * 16 + nl) * 136 + l * 8] = o;
    }
    __syncthreads();

    // Phase B: GEMM. wave w -> col tiles {2w, 2w+1}, 4 row tiles; defer writes.
    int w = tid >> 6, lane = tid & 63;
    int c0 = 2 * w, c1 = 2 * w + 1;
    f32x4 ac0[4], ac1[4];
    #pragma unroll
    for (int t = 0; t < 4; t++) {
        bfrag a[4];
        #pragma unroll
        for (int kk = 0; kk < 4; kk++)
            a[kk] = *(const bfrag*)&hs[(t * 16 + (lane & 15)) * 136 + (lane >> 4) * 8 + kk * 32];
        ac0[t] = (f32x4){0.f, 0.f, 0.f, 0.f};
        ac1[t] = (f32x4){0.f, 0.f, 0.f, 0.f};
        #pragma unroll
        for (int kk = 0; kk < 4; kk++) {
            bfrag bh0 = *(const bfrag*)&Bfr[(kk * 8 + c0) * 64 + lane];
            bfrag bl0 = *(const bfrag*)&Bfr[2048 + (kk * 8 + c0) * 64 + lane];
            bfrag bh1 = *(const bfrag*)&Bfr[(kk * 8 + c1) * 64 + lane];
            bfrag bl1 = *(const bfrag*)&Bfr[2048 + (kk * 8 + c1) * 64 + lane];
            ac0[t] = __builtin_amdgcn_mfma_f32_16x16x32_bf16(a[kk], bh0, ac0[t], 0, 0, 0);
            ac0[t] = __builtin_amdgcn_mfma_f32_16x16x32_bf16(a[kk], bl0, ac0[t], 0, 0, 0);
            ac1[t] = __builtin_amdgcn_mfma_f32_16x16x32_bf16(a[kk], bh1, ac1[t], 0, 0, 0);
            ac1[t] = __builtin_amdgcn_mfma_f32_16x16x32_bf16(a[kk], bl1, ac1[t], 0, 0, 0);
        }
    }
    __syncthreads();   // all hs reads done; reuse hs for output
    #pragma unroll
    for (int t = 0; t < 4; t++) {
        #pragma unroll
        for (int r = 0; r < 4; r++) {
            int rowt = (lane >> 4) * 4 + r;
            float dv = dinv[min(base + t * 16 + rowt, nnodes - 1)];
            hs[(t * 16 + rowt) * 136 + c0 * 16 + (lane & 15)] = (ushort)bf16rne(ac0[t][r] * dv);
            hs[(t * 16 + rowt) * 136 + c1 * 16 + (lane & 15)] = (ushort)bf16rne(ac1[t][r] * dv);
        }
    }
    __syncthreads();
    #pragma unroll
    for (int i = 0; i < 4; i++) {
        int id = tid + i * 256;       // 0..1023
        int row = id >> 4, q = id & 15;
        int grow = base + row;
        if (grow < nnodes)
            ((uint4*)Yn)[(size_t)grow * 16 + q] = *(const uint4*)&hs[row * 136 + q * 8];
    }
}

// final aggregate (layer 3): writes h3 bf16. 16 lanes/node, 16 nodes per 256-thr block.
__global__ __launch_bounds__(256) void k_aggregate(const uint4* __restrict__ H4, const int* __restrict__ rowptr,
                                                   const int* __restrict__ rowend,
                                                   const int* __restrict__ csr_src,
                                                   const float* __restrict__ dinv,
                                                   const float* __restrict__ bias, const float* __restrict__ gamma,
                                                   const float* __restrict__ beta,
                                                   uint4* __restrict__ out4, int nnodes) {
    int tid = blockIdx.x * 256 + threadIdx.x;
    int node = tid >> 4;
    int l = tid & 15;
    if (node >= nnodes) return;
    float acc[8], r[8];
    agg_body(H4, node, l, rowptr, rowend, csr_src, acc);
    bn_relu(acc, dinv[node], l, bias, gamma, beta, r);
    uint4 o;
    o.x = bf16rne(r[0]) | (bf16rne(r[1]) << 16);
    o.y = bf16rne(r[2]) | (bf16rne(r[3]) << 16);
    o.z = bf16rne(r[4]) | (bf16rne(r[5]) << 16);
    o.w = bf16rne(r[6]) | (bf16rne(r[7]) << 16);
    out4[(size_t)node * 16 + l] = o;
}

// pooled sums from bf16 H: 64 consecutive nodes per 64-thread block; batch sorted.
__global__ __launch_bounds__(64) void k_pool(const unsigned* __restrict__ Hf, const int* __restrict__ batch,
                                             float* __restrict__ pooled, float* __restrict__ cnt, int nnodes) {
    int t = threadIdx.x;
    int base = blockIdx.x * 64;
    if (base >= nnodes) return;
    int end = min(base + 64, nnodes);
    float ax = 0.f, ay = 0.f; int run = 0;
    int cur = batch[base];
    for (int i = base; i < end; i++) {
        int bg = batch[i];
        if (bg != cur) {
            atomicAdd(&pooled[(size_t)cur * 128 + 2 * t], ax);
            atomicAdd(&pooled[(size_t)cur * 128 + 2 * t + 1], ay);
            if (t == 0) atomicAdd(&cnt[cur], (float)run);
            ax = 0.f; ay = 0.f; run = 0; cur = bg;
        }
        unsigned u = Hf[(size_t)i * 64 + t];
        ax += bflo(u);
        ay += bfhi(u);
        run++;
    }
    atomicAdd(&pooled[(size_t)cur * 128 + 2 * t], ax);
    atomicAdd(&pooled[(size_t)cur * 128 + 2 * t + 1], ay);
    if (t == 0) atomicAdd(&cnt[cur], (float)run);
}

// classifier: one 64-thread block per graph. 128 -> 64 (relu) -> 10
__global__ __launch_bounds__(64) void k_classifier(const float* __restrict__ pooled, const float* __restrict__ cnt,
                                                   const float* __restrict__ Wc1, const float* __restrict__ bc1,
                                                   const float* __restrict__ Wc2, const float* __restrict__ bc2,
                                                   float* __restrict__ outp, int ngraphs) {
    __shared__ float p[128];
    __shared__ float z[64];
    int g = blockIdx.x;
    int tid = threadIdx.x;
    float inv = 1.0f / fmaxf(cnt[g], 1.0f);
    p[tid]      = pooled[(size_t)g * 128 + tid] * inv;
    p[tid + 64] = pooled[(size_t)g * 128 + 64 + tid] * inv;
    __syncthreads();
    float a = bc1[tid];
    #pragma unroll 8
    for (int k = 0; k < 128; k++) a += p[k] * Wc1[k * 64 + tid];
    z[tid] = fmaxf(a, 0.f);
    __syncthreads();
    if (tid < 10) {
        float o = bc2[tid];
        #pragma unroll 8
        for (int j = 0; j < 64; j++) o += z[j] * Wc2[j * 10 + tid];
        outp[(size_t)g * 10 + tid] = o;
    }
}

// ---------------- launch ----------------

static inline size_t align16(size_t v) { return (v + 15) & ~(size_t)15; }

extern "C" void kernel_launch(void* const* d_in, const int* in_sizes, int n_in,
                              void* d_out, int out_size, void* d_ws, size_t ws_size,
                              hipStream_t stream) {
    const float* x      = (const float*)d_in[0];
    const int*   ei     = (const int*)d_in[1];
    const int*   batch  = (const int*)d_in[2];
    const float* W1 = (const float*)d_in[3];  const float* b1 = (const float*)d_in[4];
    const float* W2 = (const float*)d_in[5];  const float* b2 = (const float*)d_in[6];
    const float* W3 = (const float*)d_in[7];  const float* b3 = (const float*)d_in[8];
    const float* g1 = (const float*)d_in[9];  const float* be1 = (const float*)d_in[10];
    const float* g2 = (const float*)d_in[11]; const float* be2 = (const float*)d_in[12];
    const float* g3 = (const float*)d_in[13]; const float* be3 = (const float*)d_in[14];
    const float* Wc1 = (const float*)d_in[15]; const float* bc1 = (const float*)d_in[16];
    const float* Wc2 = (const float*)d_in[17]; const float* bc2 = (const float*)d_in[18];

    const int N = in_sizes[0] / 128;
    const int E = in_sizes[1] / 2;
    const int G = out_size / 10;
    const int* srcp = ei;
    const int* dstp = ei + E;
    const int NB = (N + 511) >> 9;   // dst buckets of 512 nodes

    // workspace layout (16B-aligned slots); bufA/bufB have +1 zero dummy row
    char* ws = (char*)d_ws;
    size_t off = 0;
    unsigned* bufA = (unsigned*)(ws + off); off = align16(off + (size_t)(N + 1) * 64 * 4);
    unsigned* bufB = (unsigned*)(ws + off); off = align16(off + (size_t)(N + 1) * 64 * 4);
    uint4* Bfr1 = (uint4*)(ws + off); off = align16(off + 4096 * 16);
    uint4* Bfr2 = (uint4*)(ws + off); off = align16(off + 4096 * 16);
    uint4* Bfr3 = (uint4*)(ws + off); off = align16(off + 4096 * 16);
    int*   csr_src = (int*)(ws + off);  off = align16(off + (size_t)NB * CSRCAP * 4);
    unsigned* binned = (unsigned*)(ws + off); off = align16(off + (size_t)NB * BCAP * 4);
    float* dinv   = (float*)(ws + off); off = align16(off + (size_t)N * 4);
    int*   rowptr = (int*)(ws + off);   off = align16(off + (size_t)N * 4);
    int*   rowend = (int*)(ws + off);   off = align16(off + (size_t)N * 4);
    int*   gcursor = (int*)(ws + off);  off = align16(off + 256 * 4);
    float* pooled = (float*)(ws + off); off = align16(off + (size_t)G * 128 * 4);
    float* cnt    = (float*)(ws + off); off = align16(off + (size_t)G * 4);
    (void)ws_size;

    int gE8 = (E + 8191) / 8192;

    // weight frags + cursor init + dummy-row zeroing (one launch)
    k_prep<<<25, 256, 0, stream>>>(W1, W2, W3, Bfr1, Bfr2, Bfr3, gcursor, bufA, bufB, N);

    // graph structure: atomic-free CSR build (over-allocated buckets, padded rows)
    k_binA<<<gE8, 256, 0, stream>>>(srcp, dstp, gcursor, binned, E);
    k_binB2<<<NB, 256, 0, stream>>>(binned, gcursor, rowptr, rowend, dinv, csr_src, N, N);

    int gGemm = (N + 127) / 128;
    int gFuse = (N + 63) / 64;
    int gAgg  = (N * 16 + 255) / 256;

    // layer 1 GEMM (fp32 input, in-register convert) -> Y1' (bufA)
    k_gemm_mfma_f32<<<gGemm, 512, 0, stream>>>(x, Bfr1, bufA, dinv, N);
    // fused layer 1 aggregate + layer 2 GEMM -> Y2' (bufB)
    k_agg_gemm<<<gFuse, 256, 0, stream>>>((const uint4*)bufA, rowptr, rowend, csr_src, dinv,
                                          b1, g1, be1, Bfr2, bufB, N);
    // fused layer 2 aggregate + layer 3 GEMM -> Y3' (bufA)
    k_agg_gemm<<<gFuse, 256, 0, stream>>>((const uint4*)bufB, rowptr, rowend, csr_src, dinv,
                                          b2, g2, be2, Bfr3, bufA, N);
    // final aggregate -> h3 (bufB)
    k_aggregate<<<gAgg, 256, 0, stream>>>((const uint4*)bufA, rowptr, rowend, csr_src, dinv,
                                          b3, g3, be3, (uint4*)bufB, N);

    // pooling
    hipMemsetAsync(pooled, 0, ((size_t)G * 128 + G) * 4, stream);
    int gPool = (N + 63) / 64;
    k_pool<<<gPool, 64, 0, stream>>>(bufB, batch, pooled, cnt, N);

    // classifier
    k_classifier<<<G, 64, 0, stream>>>(pooled, cnt, Wc1, bc1, Wc2, bc2, (float*)d_out, G);
}

// Round 18
// 286.763 us; speedup vs baseline: 1.0371x; 1.0322x over previous
//
#include <hip/hip_runtime.h>
#include <hip/hip_bf16.h>

#define INV1P 0.9999950000374997f
#define BCAP 16384
#define CSRCAP 20480

typedef __attribute__((ext_vector_type(8))) short bfrag;   // 8 x bf16 (4 VGPR)
typedef __attribute__((ext_vector_type(4))) float f32x4;   // MFMA accumulator

static __device__ __forceinline__ unsigned bf16rne(float f) {
    unsigned u = __float_as_uint(f);
    return (u + 0x7fffu + ((u >> 16) & 1u)) >> 16;
}
static __device__ __forceinline__ float bflo(unsigned u) { return __uint_as_float(u << 16); }
static __device__ __forceinline__ float bfhi(unsigned u) { return __uint_as_float(u & 0xffff0000u); }

// ---------------- graph-structure kernels (atomic-free CSR build) ----------------

// pass A: bin edges by dst-bucket. 8192 edges/block, packed (src | dst_low<<17).
__global__ __launch_bounds__(256) void k_binA(const int* __restrict__ src, const int* __restrict__ dst,
                                              int* __restrict__ gcursor, unsigned* __restrict__ binned, int e) {
    __shared__ unsigned pk[8192];
    __shared__ unsigned char bk[8192];
    __shared__ int hist[256];
    __shared__ int base[256];
    int tid = threadIdx.x;
    hist[tid] = 0;
    __syncthreads();
    int cbase = blockIdx.x * 8192;
    int cnt = min(8192, e - cbase);
    for (int j = tid; j < cnt; j += 256) {
        int s = src[cbase + j], d = dst[cbase + j];
        unsigned b = (unsigned)d >> 9;
        pk[j] = (unsigned)s | (((unsigned)d & 511u) << 17);
        bk[j] = (unsigned char)b;
        atomicAdd(&hist[b], 1);
    }
    __syncthreads();
    int h = hist[tid];
    base[tid] = (h > 0) ? atomicAdd(&gcursor[tid], h) : 0;
    hist[tid] = 0;
    __syncthreads();
    for (int j = tid; j < cnt; j += 256) {
        unsigned b = bk[j];
        int off = atomicAdd(&hist[b], 1);
        binned[base[b] + off] = pk[j];
    }
}

// pass B: one block per bucket. Pass 1: count per-node -> dinv, rowptr/rowend
// (padded to multiple of 8, pad slots = dummy index). Pass 2: scatter to CSR.
__global__ __launch_bounds__(256) void k_binB2(const unsigned* __restrict__ binned,
                                               const int* __restrict__ gcursor,
                                               int* __restrict__ rowptr, int* __restrict__ rowend,
                                               float* __restrict__ dinv,
                                               int* __restrict__ csr_src, int n, int dummy) {
    __shared__ int cur[512];
    __shared__ int lrp[512];
    __shared__ int ssum[256];
    int b = blockIdx.x, tid = threadIdx.x;
    int nstart = b << 9;
    int nn = min(512, n - nstart);
    int cntb = gcursor[b] - b * BCAP;
    int s0 = b * BCAP, s1 = s0 + cntb;
    int cb = b * CSRCAP;
    cur[tid] = 0; cur[tid + 256] = 0;
    __syncthreads();
    for (int j = s0 + tid; j < s1; j += 256)
        atomicAdd(&cur[(binned[j] >> 17) & 511], 1);
    __syncthreads();
    int c0 = cur[2 * tid], c1 = cur[2 * tid + 1];
    int p0 = (c0 + 7) & ~7, p1 = (c1 + 7) & ~7;
    int pair = p0 + p1;
    ssum[tid] = pair;
    __syncthreads();
    for (int off = 1; off < 256; off <<= 1) {
        int t2 = (tid >= off) ? ssum[tid - off] : 0;
        __syncthreads();
        ssum[tid] += t2;
        __syncthreads();
    }
    int e0 = ssum[tid] - pair;     // exclusive (padded) for elem 2t
    int e1 = e0 + p0;
    int st0 = cb + e0, st1 = cb + e1;
    lrp[2 * tid] = st0;
    lrp[2 * tid + 1] = st1;
    if (2 * tid < nn) {
        rowptr[nstart + 2 * tid] = st0;
        rowend[nstart + 2 * tid] = st0 + p0;
        dinv[nstart + 2 * tid] = rsqrtf((float)(c0 + 1));
    }
    if (2 * tid + 1 < nn) {
        rowptr[nstart + 2 * tid + 1] = st1;
        rowend[nstart + 2 * tid + 1] = st1 + p1;
        dinv[nstart + 2 * tid + 1] = rsqrtf((float)(c1 + 1));
    }
    // pad-fill with dummy index (zero row in H)
    for (int k = c0; k < p0; k++) csr_src[st0 + k] = dummy;
    for (int k = c1; k < p1; k++) csr_src[st1 + k] = dummy;
    cur[2 * tid] = 0; cur[2 * tid + 1] = 0;
    __syncthreads();
    for (int j = s0 + tid; j < s1; j += 256) {
        unsigned p = binned[j];
        int nl = (p >> 17) & 511;
        int idx = atomicAdd(&cur[nl], 1);
        csr_src[lrp[nl] + idx] = p & 0x1ffff;
    }
}

// ---------------- dense kernels ----------------

// Build MFMA B-operand fragments from fp32 W[128][128] (row-major, W[k][n]).
// part 0 = bf16_hi(W), part 1 = bf16(W - hi)  (split for accuracy).
static __device__ __forceinline__ void prepw_body(const float* __restrict__ W, uint4* __restrict__ Bf, int blk) {
    int id = blk * 256 + threadIdx.x;          // 0..2047
    int lane = id & 63;
    int e = id >> 6;                            // 0..31
    int kk = e >> 3, c = e & 7;
    int kbase = kk * 32 + (lane >> 4) * 8;
    int col = c * 16 + (lane & 15);
    unsigned hi[8], lo[8];
    #pragma unroll
    for (int j = 0; j < 8; j++) {
        float w = W[(kbase + j) * 128 + col];
        unsigned h = bf16rne(w);
        float rh = __uint_as_float(h << 16);
        unsigned l = bf16rne(w - rh);
        hi[j] = h; lo[j] = l;
    }
    uint4 H = make_uint4(hi[0] | (hi[1] << 16), hi[2] | (hi[3] << 16),
                         hi[4] | (hi[5] << 16), hi[6] | (hi[7] << 16));
    uint4 L = make_uint4(lo[0] | (lo[1] << 16), lo[2] | (lo[3] << 16),
                         lo[4] | (lo[5] << 16), lo[6] | (lo[7] << 16));
    Bf[e * 64 + lane] = H;
    Bf[2048 + e * 64 + lane] = L;
}

// merged prep: blocks 0-23 build W frags; block 24 inits cursors + dummy rows.
__global__ __launch_bounds__(256) void k_prep(const float* __restrict__ W1, const float* __restrict__ W2,
                                              const float* __restrict__ W3,
                                              uint4* __restrict__ Bf1, uint4* __restrict__ Bf2,
                                              uint4* __restrict__ Bf3,
                                              int* __restrict__ gcursor,
                                              unsigned* __restrict__ bufA, unsigned* __restrict__ bufB, int n) {
    int b = blockIdx.x;
    if (b < 8)       prepw_body(W1, Bf1, b);
    else if (b < 16) prepw_body(W2, Bf2, b - 8);
    else if (b < 24) prepw_body(W3, Bf3, b - 16);
    else {
        int t = threadIdx.x;
        gcursor[t] = t * BCAP;
        if (t < 64)  bufA[(size_t)n * 64 + t] = 0;
        else if (t < 128) bufB[(size_t)n * 64 + (t - 64)] = 0;
    }
}

// common MFMA GEMM body (128 rows/block): a[4] fragments already loaded.
// Y'[n,128](bf16) = (A @ (Whi+Wlo)) * dinv[row]. 512 threads = 8 waves.
static __device__ __forceinline__ void gemm_body(unsigned* __restrict__ Y, const float* __restrict__ dinv,
                                                 int nrows, int rowbase, bfrag* a, uint4* bs) {
    int tid = threadIdx.x;
    int w = tid >> 6, lane = tid & 63;
    __syncthreads();   // bs staged
    f32x4 acc[8];
    #pragma unroll
    for (int c = 0; c < 8; c++) acc[c] = (f32x4){0.f, 0.f, 0.f, 0.f};
    #pragma unroll
    for (int kk = 0; kk < 4; kk++) {
        #pragma unroll
        for (int c = 0; c < 8; c++) {
            bfrag bh = *(const bfrag*)&bs[(kk * 8 + c) * 64 + lane];
            bfrag bl = *(const bfrag*)&bs[2048 + (kk * 8 + c) * 64 + lane];
            acc[c] = __builtin_amdgcn_mfma_f32_16x16x32_bf16(a[kk], bh, acc[c], 0, 0, 0);
            acc[c] = __builtin_amdgcn_mfma_f32_16x16x32_bf16(a[kk], bl, acc[c], 0, 0, 0);
        }
    }
    int rb = rowbase + w * 16 + (lane >> 4) * 4;
    float dv[4];
    #pragma unroll
    for (int r = 0; r < 4; r++) dv[r] = dinv[min(rb + r, nrows - 1)];
    __syncthreads();
    char* epib = (char*)bs;
    ushort* epi = (ushort*)(epib + w * 4352);
    #pragma unroll
    for (int c = 0; c < 8; c++) {
        #pragma unroll
        for (int r = 0; r < 4; r++) {
            int rr = (lane >> 4) * 4 + r;
            epi[rr * 136 + c * 16 + (lane & 15)] = (ushort)bf16rne(acc[c][r] * dv[r]);
        }
    }
    __syncthreads();
    #pragma unroll
    for (int i = 0; i < 4; i++) {
        int id = tid + i * 512;
        int rr = id >> 4, q = id & 15;
        int grow = rowbase + rr;
        if (grow < nrows) {
            uint4 v = *(const uint4*)(epib + (rr >> 4) * 4352 + (rr & 15) * 272 + q * 16);
            ((uint4*)Y)[(size_t)grow * 16 + q] = v;
        }
    }
}

// layer-1: reads fp32 X, converts to bf16 fragments in-register.
__global__ __launch_bounds__(512) void k_gemm_mfma_f32(const float* __restrict__ X,
                                                       const uint4* __restrict__ Bfr,
                                                       unsigned* __restrict__ Y, const float* __restrict__ dinv,
                                                       int nrows) {
    __shared__ uint4 bs[4096];
    int tid = threadIdx.x;
    int w = tid >> 6, lane = tid & 63;
    int rowbase = blockIdx.x * 128;
    #pragma unroll
    for (int i = 0; i < 8; i++) bs[tid + i * 512] = Bfr[tid + i * 512];
    int row = rowbase + w * 16 + (lane & 15);
    int rowc = min(row, nrows - 1);
    const float4* X4 = (const float4*)X;
    bfrag a[4];
    #pragma unroll
    for (int kk = 0; kk < 4; kk++) {
        float4 f0 = X4[(size_t)rowc * 32 + kk * 8 + (lane >> 4) * 2];
        float4 f1 = X4[(size_t)rowc * 32 + kk * 8 + (lane >> 4) * 2 + 1];
        uint4 av = make_uint4(bf16rne(f0.x) | (bf16rne(f0.y) << 16),
                              bf16rne(f0.z) | (bf16rne(f0.w) << 16),
                              bf16rne(f1.x) | (bf16rne(f1.y) << 16),
                              bf16rne(f1.z) | (bf16rne(f1.w) << 16));
        a[kk] = *(const bfrag*)&av;
    }
    gemm_body(Y, dinv, nrows, rowbase, a, bs);
}

// aggregate inner body: accumulate padded CSR gathers into acc[8] (fp32).
static __device__ __forceinline__ void agg_body(const uint4* __restrict__ H4, int nodec, int l,
                                                const int* __restrict__ rowptr, const int* __restrict__ rowend,
                                                const int* __restrict__ csr_src, float* acc) {
    {
        uint4 hv = H4[(size_t)nodec * 16 + l];   // Y'[dst] (self term, pre-scaled)
        acc[0] = bflo(hv.x); acc[1] = bfhi(hv.x);
        acc[2] = bflo(hv.y); acc[3] = bfhi(hv.y);
        acc[4] = bflo(hv.z); acc[5] = bfhi(hv.z);
        acc[6] = bflo(hv.w); acc[7] = bfhi(hv.w);
    }
    int s = rowptr[nodec], e = rowend[nodec];
    const int4* csr4 = (const int4*)csr_src;   // rowptr multiples of 8 -> 32B aligned
    int4 ia, ib;
    if (s < e) {
        ia = csr4[(s >> 2)];
        ib = csr4[(s >> 2) + 1];
    }
    for (int j = s; j < e; j += 8) {
        uint4 vv[8];
        vv[0] = H4[(size_t)ia.x * 16 + l];
        vv[1] = H4[(size_t)ia.y * 16 + l];
        vv[2] = H4[(size_t)ia.z * 16 + l];
        vv[3] = H4[(size_t)ia.w * 16 + l];
        vv[4] = H4[(size_t)ib.x * 16 + l];
        vv[5] = H4[(size_t)ib.y * 16 + l];
        vv[6] = H4[(size_t)ib.z * 16 + l];
        vv[7] = H4[(size_t)ib.w * 16 + l];
        int jn = j + 8;
        if (jn < e) {
            ia = csr4[(jn >> 2)];
            ib = csr4[(jn >> 2) + 1];
        }
        #pragma unroll
        for (int q = 0; q < 8; q++) {
            acc[0] += bflo(vv[q].x); acc[1] += bfhi(vv[q].x);
            acc[2] += bflo(vv[q].y); acc[3] += bfhi(vv[q].y);
            acc[4] += bflo(vv[q].z); acc[5] += bfhi(vv[q].z);
            acc[6] += bflo(vv[q].w); acc[7] += bfhi(vv[q].w);
        }
    }
}

// BN+ReLU epilogue on acc[8] -> r[8]
static __device__ __forceinline__ void bn_relu(const float* acc, float dn, int l,
                                               const float* __restrict__ bias, const float* __restrict__ gamma,
                                               const float* __restrict__ beta, float* r) {
    float4 bi0 = ((const float4*)bias)[l * 2],  bi1 = ((const float4*)bias)[l * 2 + 1];
    float4 ga0 = ((const float4*)gamma)[l * 2], ga1 = ((const float4*)gamma)[l * 2 + 1];
    float4 be0 = ((const float4*)beta)[l * 2],  be1 = ((const float4*)beta)[l * 2 + 1];
    float g[8] = {ga0.x, ga0.y, ga0.z, ga0.w, ga1.x, ga1.y, ga1.z, ga1.w};
    float bb[8] = {bi0.x, bi0.y, bi0.z, bi0.w, bi1.x, bi1.y, bi1.z, bi1.w};
    float bt[8] = {be0.x, be0.y, be0.z, be0.w, be1.x, be1.y, be1.z, be1.w};
    #pragma unroll
    for (int i = 0; i < 8; i++) {
        float t = g[i] * INV1P;
        r[i] = fmaxf(fmaf(t * dn, acc[i], fmaf(t, bb[i], bt[i])), 0.f);
    }
}

// FUSED: aggregate layer i (16 nodes/block, identical shape to standalone
// aggregate: 1 agg_body per thread, 6250 blocks) -> h in LDS (4.25 KB) ->
// 16-row GEMM tile (4 waves x 2 col-tiles, B-frags streamed from L2-hot Bfr)
// -> Y'_{i+1}. r17 lesson: 64 nodes/block serialized 4 agg_bodies per thread
// and quartered block count -> gather-MLP starved (71 us vs 58 standalone).
__global__ __launch_bounds__(256) void k_agg_gemm(const uint4* __restrict__ H4,
                                                  const int* __restrict__ rowptr, const int* __restrict__ rowend,
                                                  const int* __restrict__ csr_src,
                                                  const float* __restrict__ dinv,
                                                  const float* __restrict__ bias, const float* __restrict__ gamma,
                                                  const float* __restrict__ beta,
                                                  const uint4* __restrict__ Bfr,
                                                  unsigned* __restrict__ Yn, int nnodes) {
    __shared__ ushort hs[16 * 136];
    int tid = threadIdx.x;
    int nl = tid >> 4;          // 0..15 node within block
    int l = tid & 15;
    int base = blockIdx.x * 16;

    // Phase A: aggregate one node per 16-lane group (same MLP as standalone)
    {
        int node = base + nl;
        int nodec = min(node, nnodes - 1);
        float acc[8], r[8];
        agg_body(H4, nodec, l, rowptr, rowend, csr_src, acc);
        bn_relu(acc, dinv[nodec], l, bias, gamma, beta, r);
        uint4 o;
        o.x = bf16rne(r[0]) | (bf16rne(r[1]) << 16);
        o.y = bf16rne(r[2]) | (bf16rne(r[3]) << 16);
        o.z = bf16rne(r[4]) | (bf16rne(r[5]) << 16);
        o.w = bf16rne(r[6]) | (bf16rne(r[7]) << 16);
        *(uint4*)&hs[nl * 136 + l * 8] = o;
    }
    __syncthreads();

    // Phase B: one 16-row GEMM tile; wave w -> col tiles {2w, 2w+1}.
    int w = tid >> 6, lane = tid & 63;
    int c0 = 2 * w, c1 = 2 * w + 1;
    bfrag a[4];
    #pragma unroll
    for (int kk = 0; kk < 4; kk++)
        a[kk] = *(const bfrag*)&hs[(lane & 15) * 136 + (lane >> 4) * 8 + kk * 32];
    f32x4 ac0 = (f32x4){0.f, 0.f, 0.f, 0.f};
    f32x4 ac1 = (f32x4){0.f, 0.f, 0.f, 0.f};
    #pragma unroll
    for (int kk = 0; kk < 4; kk++) {
        bfrag bh0 = *(const bfrag*)&Bfr[(kk * 8 + c0) * 64 + lane];
        bfrag bl0 = *(const bfrag*)&Bfr[2048 + (kk * 8 + c0) * 64 + lane];
        bfrag bh1 = *(const bfrag*)&Bfr[(kk * 8 + c1) * 64 + lane];
        bfrag bl1 = *(const bfrag*)&Bfr[2048 + (kk * 8 + c1) * 64 + lane];
        ac0 = __builtin_amdgcn_mfma_f32_16x16x32_bf16(a[kk], bh0, ac0, 0, 0, 0);
        ac0 = __builtin_amdgcn_mfma_f32_16x16x32_bf16(a[kk], bl0, ac0, 0, 0, 0);
        ac1 = __builtin_amdgcn_mfma_f32_16x16x32_bf16(a[kk], bh1, ac1, 0, 0, 0);
        ac1 = __builtin_amdgcn_mfma_f32_16x16x32_bf16(a[kk], bl1, ac1, 0, 0, 0);
    }
    __syncthreads();   // all hs reads done; reuse hs for output
    #pragma unroll
    for (int r = 0; r < 4; r++) {
        int rowt = (lane >> 4) * 4 + r;
        float dv = dinv[min(base + rowt, nnodes - 1)];
        hs[rowt * 136 + c0 * 16 + (lane & 15)] = (ushort)bf16rne(ac0[r] * dv);
        hs[rowt * 136 + c1 * 16 + (lane & 15)] = (ushort)bf16rne(ac1[r] * dv);
    }
    __syncthreads();
    {
        int row = tid >> 4, q = tid & 15;
        int grow = base + row;
        if (grow < nnodes)
            ((uint4*)Yn)[(size_t)grow * 16 + q] = *(const uint4*)&hs[row * 136 + q * 8];
    }
}

// final aggregate (layer 3): writes h3 bf16. 16 lanes/node, 16 nodes per 256-thr block.
__global__ __launch_bounds__(256) void k_aggregate(const uint4* __restrict__ H4, const int* __restrict__ rowptr,
                                                   const int* __restrict__ rowend,
                                                   const int* __restrict__ csr_src,
                                                   const float* __restrict__ dinv,
                                                   const float* __restrict__ bias, const float* __restrict__ gamma,
                                                   const float* __restrict__ beta,
                                                   uint4* __restrict__ out4, int nnodes) {
    int tid = blockIdx.x * 256 + threadIdx.x;
    int node = tid >> 4;
    int l = tid & 15;
    if (node >= nnodes) return;
    float acc[8], r[8];
    agg_body(H4, node, l, rowptr, rowend, csr_src, acc);
    bn_relu(acc, dinv[node], l, bias, gamma, beta, r);
    uint4 o;
    o.x = bf16rne(r[0]) | (bf16rne(r[1]) << 16);
    o.y = bf16rne(r[2]) | (bf16rne(r[3]) << 16);
    o.z = bf16rne(r[4]) | (bf16rne(r[5]) << 16);
    o.w = bf16rne(r[6]) | (bf16rne(r[7]) << 16);
    out4[(size_t)node * 16 + l] = o;
}

// pooled sums from bf16 H: 64 consecutive nodes per 64-thread block; batch sorted.
__global__ __launch_bounds__(64) void k_pool(const unsigned* __restrict__ Hf, const int* __restrict__ batch,
                                             float* __restrict__ pooled, float* __restrict__ cnt, int nnodes) {
    int t = threadIdx.x;
    int base = blockIdx.x * 64;
    if (base >= nnodes) return;
    int end = min(base + 64, nnodes);
    float ax = 0.f, ay = 0.f; int run = 0;
    int cur = batch[base];
    for (int i = base; i < end; i++) {
        int bg = batch[i];
        if (bg != cur) {
            atomicAdd(&pooled[(size_t)cur * 128 + 2 * t], ax);
            atomicAdd(&pooled[(size_t)cur * 128 + 2 * t + 1], ay);
            if (t == 0) atomicAdd(&cnt[cur], (float)run);
            ax = 0.f; ay = 0.f; run = 0; cur = bg;
        }
        unsigned u = Hf[(size_t)i * 64 + t];
        ax += bflo(u);
        ay += bfhi(u);
        run++;
    }
    atomicAdd(&pooled[(size_t)cur * 128 + 2 * t], ax);
    atomicAdd(&pooled[(size_t)cur * 128 + 2 * t + 1], ay);
    if (t == 0) atomicAdd(&cnt[cur], (float)run);
}

// classifier: one 64-thread block per graph. 128 -> 64 (relu) -> 10
__global__ __launch_bounds__(64) void k_classifier(const float* __restrict__ pooled, const float* __restrict__ cnt,
                                                   const float* __restrict__ Wc1, const float* __restrict__ bc1,
                                                   const float* __restrict__ Wc2, const float* __restrict__ bc2,
                                                   float* __restrict__ outp, int ngraphs) {
    __shared__ float p[128];
    __shared__ float z[64];
    int g = blockIdx.x;
    int tid = threadIdx.x;
    float inv = 1.0f / fmaxf(cnt[g], 1.0f);
    p[tid]      = pooled[(size_t)g * 128 + tid] * inv;
    p[tid + 64] = pooled[(size_t)g * 128 + 64 + tid] * inv;
    __syncthreads();
    float a = bc1[tid];
    #pragma unroll 8
    for (int k = 0; k < 128; k++) a += p[k] * Wc1[k * 64 + tid];
    z[tid] = fmaxf(a, 0.f);
    __syncthreads();
    if (tid < 10) {
        float o = bc2[tid];
        #pragma unroll 8
        for (int j = 0; j < 64; j++) o += z[j] * Wc2[j * 10 + tid];
        outp[(size_t)g * 10 + tid] = o;
    }
}

// ---------------- launch ----------------

static inline size_t align16(size_t v) { return (v + 15) & ~(size_t)15; }

extern "C" void kernel_launch(void* const* d_in, const int* in_sizes, int n_in,
                              void* d_out, int out_size, void* d_ws, size_t ws_size,
                              hipStream_t stream) {
    const float* x      = (const float*)d_in[0];
    const int*   ei     = (const int*)d_in[1];
    const int*   batch  = (const int*)d_in[2];
    const float* W1 = (const float*)d_in[3];  const float* b1 = (const float*)d_in[4];
    const float* W2 = (const float*)d_in[5];  const float* b2 = (const float*)d_in[6];
    const float* W3 = (const float*)d_in[7];  const float* b3 = (const float*)d_in[8];
    const float* g1 = (const float*)d_in[9];  const float* be1 = (const float*)d_in[10];
    const float* g2 = (const float*)d_in[11]; const float* be2 = (const float*)d_in[12];
    const float* g3 = (const float*)d_in[13]; const float* be3 = (const float*)d_in[14];
    const float* Wc1 = (const float*)d_in[15]; const float* bc1 = (const float*)d_in[16];
    const float* Wc2 = (const float*)d_in[17]; const float* bc2 = (const float*)d_in[18];

    const int N = in_sizes[0] / 128;
    const int E = in_sizes[1] / 2;
    const int G = out_size / 10;
    const int* srcp = ei;
    const int* dstp = ei + E;
    const int NB = (N + 511) >> 9;   // dst buckets of 512 nodes

    // workspace layout (16B-aligned slots); bufA/bufB have +1 zero dummy row
    char* ws = (char*)d_ws;
    size_t off = 0;
    unsigned* bufA = (unsigned*)(ws + off); off = align16(off + (size_t)(N + 1) * 64 * 4);
    unsigned* bufB = (unsigned*)(ws + off); off = align16(off + (size_t)(N + 1) * 64 * 4);
    uint4* Bfr1 = (uint4*)(ws + off); off = align16(off + 4096 * 16);
    uint4* Bfr2 = (uint4*)(ws + off); off = align16(off + 4096 * 16);
    uint4* Bfr3 = (uint4*)(ws + off); off = align16(off + 4096 * 16);
    int*   csr_src = (int*)(ws + off);  off = align16(off + (size_t)NB * CSRCAP * 4);
    unsigned* binned = (unsigned*)(ws + off); off = align16(off + (size_t)NB * BCAP * 4);
    float* dinv   = (float*)(ws + off); off = align16(off + (size_t)N * 4);
    int*   rowptr = (int*)(ws + off);   off = align16(off + (size_t)N * 4);
    int*   rowend = (int*)(ws + off);   off = align16(off + (size_t)N * 4);
    int*   gcursor = (int*)(ws + off);  off = align16(off + 256 * 4);
    float* pooled = (float*)(ws + off); off = align16(off + (size_t)G * 128 * 4);
    float* cnt    = (float*)(ws + off); off = align16(off + (size_t)G * 4);
    (void)ws_size;

    int gE8 = (E + 8191) / 8192;

    // weight frags + cursor init + dummy-row zeroing (one launch)
    k_prep<<<25, 256, 0, stream>>>(W1, W2, W3, Bfr1, Bfr2, Bfr3, gcursor, bufA, bufB, N);

    // graph structure: atomic-free CSR build (over-allocated buckets, padded rows)
    k_binA<<<gE8, 256, 0, stream>>>(srcp, dstp, gcursor, binned, E);
    k_binB2<<<NB, 256, 0, stream>>>(binned, gcursor, rowptr, rowend, dinv, csr_src, N, N);

    int gGemm = (N + 127) / 128;
    int gFuse = (N + 15) / 16;
    int gAgg  = (N * 16 + 255) / 256;

    // layer 1 GEMM (fp32 input, in-register convert) -> Y1' (bufA)
    k_gemm_mfma_f32<<<gGemm, 512, 0, stream>>>(x, Bfr1, bufA, dinv, N);
    // fused layer 1 aggregate + layer 2 GEMM -> Y2' (bufB)
    k_agg_gemm<<<gFuse, 256, 0, stream>>>((const uint4*)bufA, rowptr, rowend, csr_src, dinv,
                                          b1, g1, be1, Bfr2, bufB, N);
    // fused layer 2 aggregate + layer 3 GEMM -> Y3' (bufA)
    k_agg_gemm<<<gFuse, 256, 0, stream>>>((const uint4*)bufB, rowptr, rowend, csr_src, dinv,
                                          b2, g2, be2, Bfr3, bufA, N);
    // final aggregate -> h3 (bufB)
    k_aggregate<<<gAgg, 256, 0, stream>>>((const uint4*)bufA, rowptr, rowend, csr_src, dinv,
                                          b3, g3, be3, (uint4*)bufB, N);

    // pooling
    hipMemsetAsync(pooled, 0, ((size_t)G * 128 + G) * 4, stream);
    int gPool = (N + 63) / 64;
    k_pool<<<gPool, 64, 0, stream>>>(bufB, batch, pooled, cnt, N);

    // classifier
    k_classifier<<<G, 64, 0, stream>>>(pooled, cnt, Wc1, bc1, Wc2, bc2, (float*)d_out, G);
}

// Round 19
// 286.761 us; speedup vs baseline: 1.0371x; 1.0000x over previous
//
#include <hip/hip_runtime.h>
#include <hip/hip_bf16.h>

#define INV1P 0.9999950000374997f
#define BCAP 16384
#define CSRCAP 20480

typedef __attribute__((ext_vector_type(8))) short bfrag;   // 8 x bf16 (4 VGPR)
typedef __attribute__((ext_vector_type(4))) float f32x4;   // MFMA accumulator

static __device__ __forceinline__ unsigned bf16rne(float f) {
    unsigned u = __float_as_uint(f);
    return (u + 0x7fffu + ((u >> 16) & 1u)) >> 16;
}
static __device__ __forceinline__ float bflo(unsigned u) { return __uint_as_float(u << 16); }
static __device__ __forceinline__ float bfhi(unsigned u) { return __uint_as_float(u & 0xffff0000u); }

// ---------------- graph-structure kernels (atomic-free CSR build) ----------------

// pass A: bin edges by dst-bucket. 8192 edges/block, packed (src | dst_low<<17).
__global__ __launch_bounds__(256) void k_binA(const int* __restrict__ src, const int* __restrict__ dst,
                                              int* __restrict__ gcursor, unsigned* __restrict__ binned, int e) {
    __shared__ unsigned pk[8192];
    __shared__ unsigned char bk[8192];
    __shared__ int hist[256];
    __shared__ int base[256];
    int tid = threadIdx.x;
    hist[tid] = 0;
    __syncthreads();
    int cbase = blockIdx.x * 8192;
    int cnt = min(8192, e - cbase);
    for (int j = tid; j < cnt; j += 256) {
        int s = src[cbase + j], d = dst[cbase + j];
        unsigned b = (unsigned)d >> 9;
        pk[j] = (unsigned)s | (((unsigned)d & 511u) << 17);
        bk[j] = (unsigned char)b;
        atomicAdd(&hist[b], 1);
    }
    __syncthreads();
    int h = hist[tid];
    base[tid] = (h > 0) ? atomicAdd(&gcursor[tid], h) : 0;
    hist[tid] = 0;
    __syncthreads();
    for (int j = tid; j < cnt; j += 256) {
        unsigned b = bk[j];
        int off = atomicAdd(&hist[b], 1);
        binned[base[b] + off] = pk[j];
    }
}

// pass B: one block per bucket. Pass 1: count per-node -> dinv, rowptr/rowend
// (padded to multiple of 8, pad slots = dummy index). Pass 2: scatter to CSR.
__global__ __launch_bounds__(256) void k_binB2(const unsigned* __restrict__ binned,
                                               const int* __restrict__ gcursor,
                                               int* __restrict__ rowptr, int* __restrict__ rowend,
                                               float* __restrict__ dinv,
                                               int* __restrict__ csr_src, int n, int dummy) {
    __shared__ int cur[512];
    __shared__ int lrp[512];
    __shared__ int ssum[256];
    int b = blockIdx.x, tid = threadIdx.x;
    int nstart = b << 9;
    int nn = min(512, n - nstart);
    int cntb = gcursor[b] - b * BCAP;
    int s0 = b * BCAP, s1 = s0 + cntb;
    int cb = b * CSRCAP;
    cur[tid] = 0; cur[tid + 256] = 0;
    __syncthreads();
    for (int j = s0 + tid; j < s1; j += 256)
        atomicAdd(&cur[(binned[j] >> 17) & 511], 1);
    __syncthreads();
    int c0 = cur[2 * tid], c1 = cur[2 * tid + 1];
    int p0 = (c0 + 7) & ~7, p1 = (c1 + 7) & ~7;
    int pair = p0 + p1;
    ssum[tid] = pair;
    __syncthreads();
    for (int off = 1; off < 256; off <<= 1) {
        int t2 = (tid >= off) ? ssum[tid - off] : 0;
        __syncthreads();
        ssum[tid] += t2;
        __syncthreads();
    }
    int e0 = ssum[tid] - pair;     // exclusive (padded) for elem 2t
    int e1 = e0 + p0;
    int st0 = cb + e0, st1 = cb + e1;
    lrp[2 * tid] = st0;
    lrp[2 * tid + 1] = st1;
    if (2 * tid < nn) {
        rowptr[nstart + 2 * tid] = st0;
        rowend[nstart + 2 * tid] = st0 + p0;
        dinv[nstart + 2 * tid] = rsqrtf((float)(c0 + 1));
    }
    if (2 * tid + 1 < nn) {
        rowptr[nstart + 2 * tid + 1] = st1;
        rowend[nstart + 2 * tid + 1] = st1 + p1;
        dinv[nstart + 2 * tid + 1] = rsqrtf((float)(c1 + 1));
    }
    // pad-fill with dummy index (zero row in H)
    for (int k = c0; k < p0; k++) csr_src[st0 + k] = dummy;
    for (int k = c1; k < p1; k++) csr_src[st1 + k] = dummy;
    cur[2 * tid] = 0; cur[2 * tid + 1] = 0;
    __syncthreads();
    for (int j = s0 + tid; j < s1; j += 256) {
        unsigned p = binned[j];
        int nl = (p >> 17) & 511;
        int idx = atomicAdd(&cur[nl], 1);
        csr_src[lrp[nl] + idx] = p & 0x1ffff;
    }
}

// ---------------- dense kernels ----------------

// Build MFMA B-operand fragments from fp32 W[128][128] (row-major, W[k][n]).
// part 0 = bf16_hi(W), part 1 = bf16(W - hi)  (split for accuracy).
static __device__ __forceinline__ void prepw_body(const float* __restrict__ W, uint4* __restrict__ Bf, int blk) {
    int id = blk * 256 + threadIdx.x;          // 0..2047
    int lane = id & 63;
    int e = id >> 6;                            // 0..31
    int kk = e >> 3, c = e & 7;
    int kbase = kk * 32 + (lane >> 4) * 8;
    int col = c * 16 + (lane & 15);
    unsigned hi[8], lo[8];
    #pragma unroll
    for (int j = 0; j < 8; j++) {
        float w = W[(kbase + j) * 128 + col];
        unsigned h = bf16rne(w);
        float rh = __uint_as_float(h << 16);
        unsigned l = bf16rne(w - rh);
        hi[j] = h; lo[j] = l;
    }
    uint4 H = make_uint4(hi[0] | (hi[1] << 16), hi[2] | (hi[3] << 16),
                         hi[4] | (hi[5] << 16), hi[6] | (hi[7] << 16));
    uint4 L = make_uint4(lo[0] | (lo[1] << 16), lo[2] | (lo[3] << 16),
                         lo[4] | (lo[5] << 16), lo[6] | (lo[7] << 16));
    Bf[e * 64 + lane] = H;
    Bf[2048 + e * 64 + lane] = L;
}

// merged prep: blocks 0-23 build W frags; block 24 inits cursors + dummy rows.
__global__ __launch_bounds__(256) void k_prep(const float* __restrict__ W1, const float* __restrict__ W2,
                                              const float* __restrict__ W3,
                                              uint4* __restrict__ Bf1, uint4* __restrict__ Bf2,
                                              uint4* __restrict__ Bf3,
                                              int* __restrict__ gcursor,
                                              unsigned* __restrict__ bufA, unsigned* __restrict__ bufB, int n) {
    int b = blockIdx.x;
    if (b < 8)       prepw_body(W1, Bf1, b);
    else if (b < 16) prepw_body(W2, Bf2, b - 8);
    else if (b < 24) prepw_body(W3, Bf3, b - 16);
    else {
        int t = threadIdx.x;
        gcursor[t] = t * BCAP;
        if (t < 64)  bufA[(size_t)n * 64 + t] = 0;
        else if (t < 128) bufB[(size_t)n * 64 + (t - 64)] = 0;
    }
}

// common MFMA GEMM body (128 rows/block): a[4] fragments already loaded.
// Y'[n,128](bf16) = (A @ (Whi+Wlo)) * dinv[row]. 512 threads = 8 waves.
static __device__ __forceinline__ void gemm_body(unsigned* __restrict__ Y, const float* __restrict__ dinv,
                                                 int nrows, int rowbase, bfrag* a, uint4* bs) {
    int tid = threadIdx.x;
    int w = tid >> 6, lane = tid & 63;
    __syncthreads();   // bs staged
    f32x4 acc[8];
    #pragma unroll
    for (int c = 0; c < 8; c++) acc[c] = (f32x4){0.f, 0.f, 0.f, 0.f};
    #pragma unroll
    for (int kk = 0; kk < 4; kk++) {
        #pragma unroll
        for (int c = 0; c < 8; c++) {
            bfrag bh = *(const bfrag*)&bs[(kk * 8 + c) * 64 + lane];
            bfrag bl = *(const bfrag*)&bs[2048 + (kk * 8 + c) * 64 + lane];
            acc[c] = __builtin_amdgcn_mfma_f32_16x16x32_bf16(a[kk], bh, acc[c], 0, 0, 0);
            acc[c] = __builtin_amdgcn_mfma_f32_16x16x32_bf16(a[kk], bl, acc[c], 0, 0, 0);
        }
    }
    int rb = rowbase + w * 16 + (lane >> 4) * 4;
    float dv[4];
    #pragma unroll
    for (int r = 0; r < 4; r++) dv[r] = dinv[min(rb + r, nrows - 1)];
    __syncthreads();
    char* epib = (char*)bs;
    ushort* epi = (ushort*)(epib + w * 4352);
    #pragma unroll
    for (int c = 0; c < 8; c++) {
        #pragma unroll
        for (int r = 0; r < 4; r++) {
            int rr = (lane >> 4) * 4 + r;
            epi[rr * 136 + c * 16 + (lane & 15)] = (ushort)bf16rne(acc[c][r] * dv[r]);
        }
    }
    __syncthreads();
    #pragma unroll
    for (int i = 0; i < 4; i++) {
        int id = tid + i * 512;
        int rr = id >> 4, q = id & 15;
        int grow = rowbase + rr;
        if (grow < nrows) {
            uint4 v = *(const uint4*)(epib + (rr >> 4) * 4352 + (rr & 15) * 272 + q * 16);
            ((uint4*)Y)[(size_t)grow * 16 + q] = v;
        }
    }
}

// layer-1: reads fp32 X, converts to bf16 fragments in-register.
__global__ __launch_bounds__(512) void k_gemm_mfma_f32(const float* __restrict__ X,
                                                       const uint4* __restrict__ Bfr,
                                                       unsigned* __restrict__ Y, const float* __restrict__ dinv,
                                                       int nrows) {
    __shared__ uint4 bs[4096];
    int tid = threadIdx.x;
    int w = tid >> 6, lane = tid & 63;
    int rowbase = blockIdx.x * 128;
    #pragma unroll
    for (int i = 0; i < 8; i++) bs[tid + i * 512] = Bfr[tid + i * 512];
    int row = rowbase + w * 16 + (lane & 15);
    int rowc = min(row, nrows - 1);
    const float4* X4 = (const float4*)X;
    bfrag a[4];
    #pragma unroll
    for (int kk = 0; kk < 4; kk++) {
        float4 f0 = X4[(size_t)rowc * 32 + kk * 8 + (lane >> 4) * 2];
        float4 f1 = X4[(size_t)rowc * 32 + kk * 8 + (lane >> 4) * 2 + 1];
        uint4 av = make_uint4(bf16rne(f0.x) | (bf16rne(f0.y) << 16),
                              bf16rne(f0.z) | (bf16rne(f0.w) << 16),
                              bf16rne(f1.x) | (bf16rne(f1.y) << 16),
                              bf16rne(f1.z) | (bf16rne(f1.w) << 16));
        a[kk] = *(const bfrag*)&av;
    }
    gemm_body(Y, dinv, nrows, rowbase, a, bs);
}

// aggregate inner body: accumulate padded CSR gathers into acc[8] (fp32).
static __device__ __forceinline__ void agg_body(const uint4* __restrict__ H4, int nodec, int l,
                                                const int* __restrict__ rowptr, const int* __restrict__ rowend,
                                                const int* __restrict__ csr_src, float* acc) {
    {
        uint4 hv = H4[(size_t)nodec * 16 + l];   // Y'[dst] (self term, pre-scaled)
        acc[0] = bflo(hv.x); acc[1] = bfhi(hv.x);
        acc[2] = bflo(hv.y); acc[3] = bfhi(hv.y);
        acc[4] = bflo(hv.z); acc[5] = bfhi(hv.z);
        acc[6] = bflo(hv.w); acc[7] = bfhi(hv.w);
    }
    int s = rowptr[nodec], e = rowend[nodec];
    const int4* csr4 = (const int4*)csr_src;   // rowptr multiples of 8 -> 32B aligned
    int4 ia, ib;
    if (s < e) {
        ia = csr4[(s >> 2)];
        ib = csr4[(s >> 2) + 1];
    }
    for (int j = s; j < e; j += 8) {
        uint4 vv[8];
        vv[0] = H4[(size_t)ia.x * 16 + l];
        vv[1] = H4[(size_t)ia.y * 16 + l];
        vv[2] = H4[(size_t)ia.z * 16 + l];
        vv[3] = H4[(size_t)ia.w * 16 + l];
        vv[4] = H4[(size_t)ib.x * 16 + l];
        vv[5] = H4[(size_t)ib.y * 16 + l];
        vv[6] = H4[(size_t)ib.z * 16 + l];
        vv[7] = H4[(size_t)ib.w * 16 + l];
        int jn = j + 8;
        if (jn < e) {
            ia = csr4[(jn >> 2)];
            ib = csr4[(jn >> 2) + 1];
        }
        #pragma unroll
        for (int q = 0; q < 8; q++) {
            acc[0] += bflo(vv[q].x); acc[1] += bfhi(vv[q].x);
            acc[2] += bflo(vv[q].y); acc[3] += bfhi(vv[q].y);
            acc[4] += bflo(vv[q].z); acc[5] += bfhi(vv[q].z);
            acc[6] += bflo(vv[q].w); acc[7] += bfhi(vv[q].w);
        }
    }
}

// BN+ReLU epilogue on acc[8] -> r[8]
static __device__ __forceinline__ void bn_relu(const float* acc, float dn, int l,
                                               const float* __restrict__ bias, const float* __restrict__ gamma,
                                               const float* __restrict__ beta, float* r) {
    float4 bi0 = ((const float4*)bias)[l * 2],  bi1 = ((const float4*)bias)[l * 2 + 1];
    float4 ga0 = ((const float4*)gamma)[l * 2], ga1 = ((const float4*)gamma)[l * 2 + 1];
    float4 be0 = ((const float4*)beta)[l * 2],  be1 = ((const float4*)beta)[l * 2 + 1];
    float g[8] = {ga0.x, ga0.y, ga0.z, ga0.w, ga1.x, ga1.y, ga1.z, ga1.w};
    float bb[8] = {bi0.x, bi0.y, bi0.z, bi0.w, bi1.x, bi1.y, bi1.z, bi1.w};
    float bt[8] = {be0.x, be0.y, be0.z, be0.w, be1.x, be1.y, be1.z, be1.w};
    #pragma unroll
    for (int i = 0; i < 8; i++) {
        float t = g[i] * INV1P;
        r[i] = fmaxf(fmaf(t * dn, acc[i], fmaf(t, bb[i], bt[i])), 0.f);
    }
}

// FUSED: aggregate layer i (16 nodes/block, identical shape to standalone
// aggregate: 1 agg_body per thread, 6250 blocks) -> h in LDS (4.25 KB) ->
// 16-row GEMM tile (4 waves x 2 col-tiles, B-frags streamed from L2-hot Bfr)
// -> Y'_{i+1}. r17 lesson: 64 nodes/block serialized 4 agg_bodies per thread
// and quartered block count -> gather-MLP starved (71 us vs 58 standalone).
__global__ __launch_bounds__(256) void k_agg_gemm(const uint4* __restrict__ H4,
                                                  const int* __restrict__ rowptr, const int* __restrict__ rowend,
                                                  const int* __restrict__ csr_src,
                                                  const float* __restrict__ dinv,
                                                  const float* __restrict__ bias, const float* __restrict__ gamma,
                                                  const float* __restrict__ beta,
                                                  const uint4* __restrict__ Bfr,
                                                  unsigned* __restrict__ Yn, int nnodes) {
    __shared__ ushort hs[16 * 136];
    int tid = threadIdx.x;
    int nl = tid >> 4;          // 0..15 node within block
    int l = tid & 15;
    int base = blockIdx.x * 16;

    // Phase A: aggregate one node per 16-lane group (same MLP as standalone)
    {
        int node = base + nl;
        int nodec = min(node, nnodes - 1);
        float acc[8], r[8];
        agg_body(H4, nodec, l, rowptr, rowend, csr_src, acc);
        bn_relu(acc, dinv[nodec], l, bias, gamma, beta, r);
        uint4 o;
        o.x = bf16rne(r[0]) | (bf16rne(r[1]) << 16);
        o.y = bf16rne(r[2]) | (bf16rne(r[3]) << 16);
        o.z = bf16rne(r[4]) | (bf16rne(r[5]) << 16);
        o.w = bf16rne(r[6]) | (bf16rne(r[7]) << 16);
        *(uint4*)&hs[nl * 136 + l * 8] = o;
    }
    __syncthreads();

    // Phase B: one 16-row GEMM tile; wave w -> col tiles {2w, 2w+1}.
    int w = tid >> 6, lane = tid & 63;
    int c0 = 2 * w, c1 = 2 * w + 1;
    bfrag a[4];
    #pragma unroll
    for (int kk = 0; kk < 4; kk++)
        a[kk] = *(const bfrag*)&hs[(lane & 15) * 136 + (lane >> 4) * 8 + kk * 32];
    f32x4 ac0 = (f32x4){0.f, 0.f, 0.f, 0.f};
    f32x4 ac1 = (f32x4){0.f, 0.f, 0.f, 0.f};
    #pragma unroll
    for (int kk = 0; kk < 4; kk++) {
        bfrag bh0 = *(const bfrag*)&Bfr[(kk * 8 + c0) * 64 + lane];
        bfrag bl0 = *(const bfrag*)&Bfr[2048 + (kk * 8 + c0) * 64 + lane];
        bfrag bh1 = *(const bfrag*)&Bfr[(kk * 8 + c1) * 64 + lane];
        bfrag bl1 = *(const bfrag*)&Bfr[2048 + (kk * 8 + c1) * 64 + lane];
        ac0 = __builtin_amdgcn_mfma_f32_16x16x32_bf16(a[kk], bh0, ac0, 0, 0, 0);
        ac0 = __builtin_amdgcn_mfma_f32_16x16x32_bf16(a[kk], bl0, ac0, 0, 0, 0);
        ac1 = __builtin_amdgcn_mfma_f32_16x16x32_bf16(a[kk], bh1, ac1, 0, 0, 0);
        ac1 = __builtin_amdgcn_mfma_f32_16x16x32_bf16(a[kk], bl1, ac1, 0, 0, 0);
    }
    __syncthreads();   // all hs reads done; reuse hs for output
    #pragma unroll
    for (int r = 0; r < 4; r++) {
        int rowt = (lane >> 4) * 4 + r;
        float dv = dinv[min(base + rowt, nnodes - 1)];
        hs[rowt * 136 + c0 * 16 + (lane & 15)] = (ushort)bf16rne(ac0[r] * dv);
        hs[rowt * 136 + c1 * 16 + (lane & 15)] = (ushort)bf16rne(ac1[r] * dv);
    }
    __syncthreads();
    {
        int row = tid >> 4, q = tid & 15;
        int grow = base + row;
        if (grow < nnodes)
            ((uint4*)Yn)[(size_t)grow * 16 + q] = *(const uint4*)&hs[row * 136 + q * 8];
    }
}

// final aggregate (layer 3): writes h3 bf16. 16 lanes/node, 16 nodes per 256-thr block.
__global__ __launch_bounds__(256) void k_aggregate(const uint4* __restrict__ H4, const int* __restrict__ rowptr,
                                                   const int* __restrict__ rowend,
                                                   const int* __restrict__ csr_src,
                                                   const float* __restrict__ dinv,
                                                   const float* __restrict__ bias, const float* __restrict__ gamma,
                                                   const float* __restrict__ beta,
                                                   uint4* __restrict__ out4, int nnodes) {
    int tid = blockIdx.x * 256 + threadIdx.x;
    int node = tid >> 4;
    int l = tid & 15;
    if (node >= nnodes) return;
    float acc[8], r[8];
    agg_body(H4, node, l, rowptr, rowend, csr_src, acc);
    bn_relu(acc, dinv[node], l, bias, gamma, beta, r);
    uint4 o;
    o.x = bf16rne(r[0]) | (bf16rne(r[1]) << 16);
    o.y = bf16rne(r[2]) | (bf16rne(r[3]) << 16);
    o.z = bf16rne(r[4]) | (bf16rne(r[5]) << 16);
    o.w = bf16rne(r[6]) | (bf16rne(r[7]) << 16);
    out4[(size_t)node * 16 + l] = o;
}

// pooled sums from bf16 H: 64 consecutive nodes per 64-thread block; batch sorted.
__global__ __launch_bounds__(64) void k_pool(const unsigned* __restrict__ Hf, const int* __restrict__ batch,
                                             float* __restrict__ pooled, float* __restrict__ cnt, int nnodes) {
    int t = threadIdx.x;
    int base = blockIdx.x * 64;
    if (base >= nnodes) return;
    int end = min(base + 64, nnodes);
    float ax = 0.f, ay = 0.f; int run = 0;
    int cur = batch[base];
    for (int i = base; i < end; i++) {
        int bg = batch[i];
        if (bg != cur) {
            atomicAdd(&pooled[(size_t)cur * 128 + 2 * t], ax);
            atomicAdd(&pooled[(size_t)cur * 128 + 2 * t + 1], ay);
            if (t == 0) atomicAdd(&cnt[cur], (float)run);
            ax = 0.f; ay = 0.f; run = 0; cur = bg;
        }
        unsigned u = Hf[(size_t)i * 64 + t];
        ax += bflo(u);
        ay += bfhi(u);
        run++;
    }
    atomicAdd(&pooled[(size_t)cur * 128 + 2 * t], ax);
    atomicAdd(&pooled[(size_t)cur * 128 + 2 * t + 1], ay);
    if (t == 0) atomicAdd(&cnt[cur], (float)run);
}

// classifier: one 64-thread block per graph. 128 -> 64 (relu) -> 10
__global__ __launch_bounds__(64) void k_classifier(const float* __restrict__ pooled, const float* __restrict__ cnt,
                                                   const float* __restrict__ Wc1, const float* __restrict__ bc1,
                                                   const float* __restrict__ Wc2, const float* __restrict__ bc2,
                                                   float* __restrict__ outp, int ngraphs) {
    __shared__ float p[128];
    __shared__ float z[64];
    int g = blockIdx.x;
    int tid = threadIdx.x;
    float inv = 1.0f / fmaxf(cnt[g], 1.0f);
    p[tid]      = pooled[(size_t)g * 128 + tid] * inv;
    p[tid + 64] = pooled[(size_t)g * 128 + 64 + tid] * inv;
    __syncthreads();
    float a = bc1[tid];
    #pragma unroll 8
    for (int k = 0; k < 128; k++) a += p[k] * Wc1[k * 64 + tid];
    z[tid] = fmaxf(a, 0.f);
    __syncthreads();
    if (tid < 10) {
        float o = bc2[tid];
        #pragma unroll 8
        for (int j = 0; j < 64; j++) o += z[j] * Wc2[j * 10 + tid];
        outp[(size_t)g * 10 + tid] = o;
    }
}

// ---------------- launch ----------------

static inline size_t align16(size_t v) { return (v + 15) & ~(size_t)15; }

extern "C" void kernel_launch(void* const* d_in, const int* in_sizes, int n_in,
                              void* d_out, int out_size, void* d_ws, size_t ws_size,
                              hipStream_t stream) {
    const float* x      = (const float*)d_in[0];
    const int*   ei     = (const int*)d_in[1];
    const int*   batch  = (const int*)d_in[2];
    const float* W1 = (const float*)d_in[3];  const float* b1 = (const float*)d_in[4];
    const float* W2 = (const float*)d_in[5];  const float* b2 = (const float*)d_in[6];
    const float* W3 = (const float*)d_in[7];  const float* b3 = (const float*)d_in[8];
    const float* g1 = (const float*)d_in[9];  const float* be1 = (const float*)d_in[10];
    const float* g2 = (const float*)d_in[11]; const float* be2 = (const float*)d_in[12];
    const float* g3 = (const float*)d_in[13]; const float* be3 = (const float*)d_in[14];
    const float* Wc1 = (const float*)d_in[15]; const float* bc1 = (const float*)d_in[16];
    const float* Wc2 = (const float*)d_in[17]; const float* bc2 = (const float*)d_in[18];

    const int N = in_sizes[0] / 128;
    const int E = in_sizes[1] / 2;
    const int G = out_size / 10;
    const int* srcp = ei;
    const int* dstp = ei + E;
    const int NB = (N + 511) >> 9;   // dst buckets of 512 nodes

    // workspace layout (16B-aligned slots); bufA/bufB have +1 zero dummy row
    char* ws = (char*)d_ws;
    size_t off = 0;
    unsigned* bufA = (unsigned*)(ws + off); off = align16(off + (size_t)(N + 1) * 64 * 4);
    unsigned* bufB = (unsigned*)(ws + off); off = align16(off + (size_t)(N + 1) * 64 * 4);
    uint4* Bfr1 = (uint4*)(ws + off); off = align16(off + 4096 * 16);
    uint4* Bfr2 = (uint4*)(ws + off); off = align16(off + 4096 * 16);
    uint4* Bfr3 = (uint4*)(ws + off); off = align16(off + 4096 * 16);
    int*   csr_src = (int*)(ws + off);  off = align16(off + (size_t)NB * CSRCAP * 4);
    unsigned* binned = (unsigned*)(ws + off); off = align16(off + (size_t)NB * BCAP * 4);
    float* dinv   = (float*)(ws + off); off = align16(off + (size_t)N * 4);
    int*   rowptr = (int*)(ws + off);   off = align16(off + (size_t)N * 4);
    int*   rowend = (int*)(ws + off);   off = align16(off + (size_t)N * 4);
    int*   gcursor = (int*)(ws + off);  off = align16(off + 256 * 4);
    float* pooled = (float*)(ws + off); off = align16(off + (size_t)G * 128 * 4);
    float* cnt    = (float*)(ws + off); off = align16(off + (size_t)G * 4);
    (void)ws_size;

    int gE8 = (E + 8191) / 8192;

    // weight frags + cursor init + dummy-row zeroing (one launch)
    k_prep<<<25, 256, 0, stream>>>(W1, W2, W3, Bfr1, Bfr2, Bfr3, gcursor, bufA, bufB, N);

    // graph structure: atomic-free CSR build (over-allocated buckets, padded rows)
    k_binA<<<gE8, 256, 0, stream>>>(srcp, dstp, gcursor, binned, E);
    k_binB2<<<NB, 256, 0, stream>>>(binned, gcursor, rowptr, rowend, dinv, csr_src, N, N);

    int gGemm = (N + 127) / 128;
    int gFuse = (N + 15) / 16;
    int gAgg  = (N * 16 + 255) / 256;

    // layer 1 GEMM (fp32 input, in-register convert) -> Y1' (bufA)
    k_gemm_mfma_f32<<<gGemm, 512, 0, stream>>>(x, Bfr1, bufA, dinv, N);
    // fused layer 1 aggregate + layer 2 GEMM -> Y2' (bufB)
    k_agg_gemm<<<gFuse, 256, 0, stream>>>((const uint4*)bufA, rowptr, rowend, csr_src, dinv,
                                          b1, g1, be1, Bfr2, bufB, N);
    // fused layer 2 aggregate + layer 3 GEMM -> Y3' (bufA)
    k_agg_gemm<<<gFuse, 256, 0, stream>>>((const uint4*)bufB, rowptr, rowend, csr_src, dinv,
                                          b2, g2, be2, Bfr3, bufA, N);
    // final aggregate -> h3 (bufB)
    k_aggregate<<<gAgg, 256, 0, stream>>>((const uint4*)bufA, rowptr, rowend, csr_src, dinv,
                                          b3, g3, be3, (uint4*)bufB, N);

    // pooling
    hipMemsetAsync(pooled, 0, ((size_t)G * 128 + G) * 4, stream);
    int gPool = (N + 63) / 64;
    k_pool<<<gPool, 64, 0, stream>>>(bufB, batch, pooled, cnt, N);

    // classifier
    k_classifier<<<G, 64, 0, stream>>>(pooled, cnt, Wc1, bc1, Wc2, bc2, (float*)d_out, G);
}

// Round 20
// 266.184 us; speedup vs baseline: 1.1173x; 1.0773x over previous
//
#include <hip/hip_runtime.h>
#include <hip/hip_bf16.h>

#define INV1P 0.9999950000374997f
#define BCAP 16384
#define CSRCAP 20480

typedef __attribute__((ext_vector_type(8))) short bfrag;   // 8 x bf16 (4 VGPR)
typedef __attribute__((ext_vector_type(4))) float f32x4;   // MFMA accumulator

static __device__ __forceinline__ unsigned bf16rne(float f) {
    unsigned u = __float_as_uint(f);
    return (u + 0x7fffu + ((u >> 16) & 1u)) >> 16;
}
static __device__ __forceinline__ float bflo(unsigned u) { return __uint_as_float(u << 16); }
static __device__ __forceinline__ float bfhi(unsigned u) { return __uint_as_float(u & 0xffff0000u); }

// ---------------- graph-structure kernels (atomic-free CSR build) ----------------

// pass A: bin edges by dst-bucket. 8192 edges/block, packed (src | dst_low<<17).
__global__ __launch_bounds__(256) void k_binA(const int* __restrict__ src, const int* __restrict__ dst,
                                              int* __restrict__ gcursor, unsigned* __restrict__ binned, int e) {
    __shared__ unsigned pk[8192];
    __shared__ unsigned char bk[8192];
    __shared__ int hist[256];
    __shared__ int base[256];
    int tid = threadIdx.x;
    hist[tid] = 0;
    __syncthreads();
    int cbase = blockIdx.x * 8192;
    int cnt = min(8192, e - cbase);
    for (int j = tid; j < cnt; j += 256) {
        int s = src[cbase + j], d = dst[cbase + j];
        unsigned b = (unsigned)d >> 9;
        pk[j] = (unsigned)s | (((unsigned)d & 511u) << 17);
        bk[j] = (unsigned char)b;
        atomicAdd(&hist[b], 1);
    }
    __syncthreads();
    int h = hist[tid];
    base[tid] = (h > 0) ? atomicAdd(&gcursor[tid], h) : 0;
    hist[tid] = 0;
    __syncthreads();
    for (int j = tid; j < cnt; j += 256) {
        unsigned b = bk[j];
        int off = atomicAdd(&hist[b], 1);
        binned[base[b] + off] = pk[j];
    }
}

// pass B: one block per bucket. Pass 1: count per-node -> dinv, rowptr/rowend
// (padded to multiple of 8, pad slots = dummy index). Pass 2: scatter to CSR.
__global__ __launch_bounds__(256) void k_binB2(const unsigned* __restrict__ binned,
                                               const int* __restrict__ gcursor,
                                               int* __restrict__ rowptr, int* __restrict__ rowend,
                                               float* __restrict__ dinv,
                                               int* __restrict__ csr_src, int n, int dummy) {
    __shared__ int cur[512];
    __shared__ int lrp[512];
    __shared__ int ssum[256];
    int b = blockIdx.x, tid = threadIdx.x;
    int nstart = b << 9;
    int nn = min(512, n - nstart);
    int cntb = gcursor[b] - b * BCAP;
    int s0 = b * BCAP, s1 = s0 + cntb;
    int cb = b * CSRCAP;
    cur[tid] = 0; cur[tid + 256] = 0;
    __syncthreads();
    for (int j = s0 + tid; j < s1; j += 256)
        atomicAdd(&cur[(binned[j] >> 17) & 511], 1);
    __syncthreads();
    int c0 = cur[2 * tid], c1 = cur[2 * tid + 1];
    int p0 = (c0 + 7) & ~7, p1 = (c1 + 7) & ~7;
    int pair = p0 + p1;
    ssum[tid] = pair;
    __syncthreads();
    for (int off = 1; off < 256; off <<= 1) {
        int t2 = (tid >= off) ? ssum[tid - off] : 0;
        __syncthreads();
        ssum[tid] += t2;
        __syncthreads();
    }
    int e0 = ssum[tid] - pair;     // exclusive (padded) for elem 2t
    int e1 = e0 + p0;
    int st0 = cb + e0, st1 = cb + e1;
    lrp[2 * tid] = st0;
    lrp[2 * tid + 1] = st1;
    if (2 * tid < nn) {
        rowptr[nstart + 2 * tid] = st0;
        rowend[nstart + 2 * tid] = st0 + p0;
        dinv[nstart + 2 * tid] = rsqrtf((float)(c0 + 1));
    }
    if (2 * tid + 1 < nn) {
        rowptr[nstart + 2 * tid + 1] = st1;
        rowend[nstart + 2 * tid + 1] = st1 + p1;
        dinv[nstart + 2 * tid + 1] = rsqrtf((float)(c1 + 1));
    }
    // pad-fill with dummy index (zero row in H)
    for (int k = c0; k < p0; k++) csr_src[st0 + k] = dummy;
    for (int k = c1; k < p1; k++) csr_src[st1 + k] = dummy;
    cur[2 * tid] = 0; cur[2 * tid + 1] = 0;
    __syncthreads();
    for (int j = s0 + tid; j < s1; j += 256) {
        unsigned p = binned[j];
        int nl = (p >> 17) & 511;
        int idx = atomicAdd(&cur[nl], 1);
        csr_src[lrp[nl] + idx] = p & 0x1ffff;
    }
}

// ---------------- dense kernels ----------------

// Build MFMA B-operand fragments from fp32 W[128][128] (row-major, W[k][n]).
// part 0 = bf16_hi(W), part 1 = bf16(W - hi)  (split for accuracy).
static __device__ __forceinline__ void prepw_body(const float* __restrict__ W, uint4* __restrict__ Bf, int blk) {
    int id = blk * 256 + threadIdx.x;          // 0..2047
    int lane = id & 63;
    int e = id >> 6;                            // 0..31
    int kk = e >> 3, c = e & 7;
    int kbase = kk * 32 + (lane >> 4) * 8;
    int col = c * 16 + (lane & 15);
    unsigned hi[8], lo[8];
    #pragma unroll
    for (int j = 0; j < 8; j++) {
        float w = W[(kbase + j) * 128 + col];
        unsigned h = bf16rne(w);
        float rh = __uint_as_float(h << 16);
        unsigned l = bf16rne(w - rh);
        hi[j] = h; lo[j] = l;
    }
    uint4 H = make_uint4(hi[0] | (hi[1] << 16), hi[2] | (hi[3] << 16),
                         hi[4] | (hi[5] << 16), hi[6] | (hi[7] << 16));
    uint4 L = make_uint4(lo[0] | (lo[1] << 16), lo[2] | (lo[3] << 16),
                         lo[4] | (lo[5] << 16), lo[6] | (lo[7] << 16));
    Bf[e * 64 + lane] = H;
    Bf[2048 + e * 64 + lane] = L;
}

// merged prep: blocks 0-23 build W frags; block 24 inits cursors + dummy rows.
__global__ __launch_bounds__(256) void k_prep(const float* __restrict__ W1, const float* __restrict__ W2,
                                              const float* __restrict__ W3,
                                              uint4* __restrict__ Bf1, uint4* __restrict__ Bf2,
                                              uint4* __restrict__ Bf3,
                                              int* __restrict__ gcursor,
                                              unsigned* __restrict__ bufA, unsigned* __restrict__ bufB, int n) {
    int b = blockIdx.x;
    if (b < 8)       prepw_body(W1, Bf1, b);
    else if (b < 16) prepw_body(W2, Bf2, b - 8);
    else if (b < 24) prepw_body(W3, Bf3, b - 16);
    else {
        int t = threadIdx.x;
        gcursor[t] = t * BCAP;
        if (t < 64)  bufA[(size_t)n * 64 + t] = 0;
        else if (t < 128) bufB[(size_t)n * 64 + (t - 64)] = 0;
    }
}

// common MFMA GEMM body (128 rows/block): a[4] fragments already loaded.
// Y'[n,128](bf16) = (A @ (Whi+Wlo)) * dinv[row]. 512 threads = 8 waves.
static __device__ __forceinline__ void gemm_body(unsigned* __restrict__ Y, const float* __restrict__ dinv,
                                                 int nrows, int rowbase, bfrag* a, uint4* bs) {
    int tid = threadIdx.x;
    int w = tid >> 6, lane = tid & 63;
    __syncthreads();   // bs staged
    f32x4 acc[8];
    #pragma unroll
    for (int c = 0; c < 8; c++) acc[c] = (f32x4){0.f, 0.f, 0.f, 0.f};
    #pragma unroll
    for (int kk = 0; kk < 4; kk++) {
        #pragma unroll
        for (int c = 0; c < 8; c++) {
            bfrag bh = *(const bfrag*)&bs[(kk * 8 + c) * 64 + lane];
            bfrag bl = *(const bfrag*)&bs[2048 + (kk * 8 + c) * 64 + lane];
            acc[c] = __builtin_amdgcn_mfma_f32_16x16x32_bf16(a[kk], bh, acc[c], 0, 0, 0);
            acc[c] = __builtin_amdgcn_mfma_f32_16x16x32_bf16(a[kk], bl, acc[c], 0, 0, 0);
        }
    }
    int rb = rowbase + w * 16 + (lane >> 4) * 4;
    float dv[4];
    #pragma unroll
    for (int r = 0; r < 4; r++) dv[r] = dinv[min(rb + r, nrows - 1)];
    __syncthreads();
    char* epib = (char*)bs;
    ushort* epi = (ushort*)(epib + w * 4352);
    #pragma unroll
    for (int c = 0; c < 8; c++) {
        #pragma unroll
        for (int r = 0; r < 4; r++) {
            int rr = (lane >> 4) * 4 + r;
            epi[rr * 136 + c * 16 + (lane & 15)] = (ushort)bf16rne(acc[c][r] * dv[r]);
        }
    }
    __syncthreads();
    #pragma unroll
    for (int i = 0; i < 4; i++) {
        int id = tid + i * 512;
        int rr = id >> 4, q = id & 15;
        int grow = rowbase + rr;
        if (grow < nrows) {
            uint4 v = *(const uint4*)(epib + (rr >> 4) * 4352 + (rr & 15) * 272 + q * 16);
            ((uint4*)Y)[(size_t)grow * 16 + q] = v;
        }
    }
}

// layer-1: reads fp32 X, converts to bf16 fragments in-register.
__global__ __launch_bounds__(512) void k_gemm_mfma_f32(const float* __restrict__ X,
                                                       const uint4* __restrict__ Bfr,
                                                       unsigned* __restrict__ Y, const float* __restrict__ dinv,
                                                       int nrows) {
    __shared__ uint4 bs[4096];
    int tid = threadIdx.x;
    int w = tid >> 6, lane = tid & 63;
    int rowbase = blockIdx.x * 128;
    #pragma unroll
    for (int i = 0; i < 8; i++) bs[tid + i * 512] = Bfr[tid + i * 512];
    int row = rowbase + w * 16 + (lane & 15);
    int rowc = min(row, nrows - 1);
    const float4* X4 = (const float4*)X;
    bfrag a[4];
    #pragma unroll
    for (int kk = 0; kk < 4; kk++) {
        float4 f0 = X4[(size_t)rowc * 32 + kk * 8 + (lane >> 4) * 2];
        float4 f1 = X4[(size_t)rowc * 32 + kk * 8 + (lane >> 4) * 2 + 1];
        uint4 av = make_uint4(bf16rne(f0.x) | (bf16rne(f0.y) << 16),
                              bf16rne(f0.z) | (bf16rne(f0.w) << 16),
                              bf16rne(f1.x) | (bf16rne(f1.y) << 16),
                              bf16rne(f1.z) | (bf16rne(f1.w) << 16));
        a[kk] = *(const bfrag*)&av;
    }
    gemm_body(Y, dinv, nrows, rowbase, a, bs);
}

// aggregate inner body: accumulate padded CSR gathers into acc[8] (fp32).
static __device__ __forceinline__ void agg_body(const uint4* __restrict__ H4, int nodec, int l,
                                                const int* __restrict__ rowptr, const int* __restrict__ rowend,
                                                const int* __restrict__ csr_src, float* acc) {
    {
        uint4 hv = H4[(size_t)nodec * 16 + l];   // Y'[dst] (self term, pre-scaled)
        acc[0] = bflo(hv.x); acc[1] = bfhi(hv.x);
        acc[2] = bflo(hv.y); acc[3] = bfhi(hv.y);
        acc[4] = bflo(hv.z); acc[5] = bfhi(hv.z);
        acc[6] = bflo(hv.w); acc[7] = bfhi(hv.w);
    }
    int s = rowptr[nodec], e = rowend[nodec];
    const int4* csr4 = (const int4*)csr_src;   // rowptr multiples of 8 -> 32B aligned
    int4 ia, ib;
    if (s < e) {
        ia = csr4[(s >> 2)];
        ib = csr4[(s >> 2) + 1];
    }
    for (int j = s; j < e; j += 8) {
        uint4 vv[8];
        vv[0] = H4[(size_t)ia.x * 16 + l];
        vv[1] = H4[(size_t)ia.y * 16 + l];
        vv[2] = H4[(size_t)ia.z * 16 + l];
        vv[3] = H4[(size_t)ia.w * 16 + l];
        vv[4] = H4[(size_t)ib.x * 16 + l];
        vv[5] = H4[(size_t)ib.y * 16 + l];
        vv[6] = H4[(size_t)ib.z * 16 + l];
        vv[7] = H4[(size_t)ib.w * 16 + l];
        int jn = j + 8;
        if (jn < e) {
            ia = csr4[(jn >> 2)];
            ib = csr4[(jn >> 2) + 1];
        }
        #pragma unroll
        for (int q = 0; q < 8; q++) {
            acc[0] += bflo(vv[q].x); acc[1] += bfhi(vv[q].x);
            acc[2] += bflo(vv[q].y); acc[3] += bfhi(vv[q].y);
            acc[4] += bflo(vv[q].z); acc[5] += bfhi(vv[q].z);
            acc[6] += bflo(vv[q].w); acc[7] += bfhi(vv[q].w);
        }
    }
}

// BN+ReLU epilogue on acc[8] -> r[8]
static __device__ __forceinline__ void bn_relu(const float* acc, float dn, int l,
                                               const float* __restrict__ bias, const float* __restrict__ gamma,
                                               const float* __restrict__ beta, float* r) {
    float4 bi0 = ((const float4*)bias)[l * 2],  bi1 = ((const float4*)bias)[l * 2 + 1];
    float4 ga0 = ((const float4*)gamma)[l * 2], ga1 = ((const float4*)gamma)[l * 2 + 1];
    float4 be0 = ((const float4*)beta)[l * 2],  be1 = ((const float4*)beta)[l * 2 + 1];
    float g[8] = {ga0.x, ga0.y, ga0.z, ga0.w, ga1.x, ga1.y, ga1.z, ga1.w};
    float bb[8] = {bi0.x, bi0.y, bi0.z, bi0.w, bi1.x, bi1.y, bi1.z, bi1.w};
    float bt[8] = {be0.x, be0.y, be0.z, be0.w, be1.x, be1.y, be1.z, be1.w};
    #pragma unroll
    for (int i = 0; i < 8; i++) {
        float t = g[i] * INV1P;
        r[i] = fmaxf(fmaf(t * dn, acc[i], fmaf(t, bb[i], bt[i])), 0.f);
    }
}

// FUSED: aggregate layer i (32 nodes/block, 512 threads, 1 agg_body/thread)
// -> h in LDS (8.7 KB) -> 32-row GEMM tile (8 waves, wave w = col tile w,
// B-frag reused across 2 row tiles -> Bfr L2 traffic halved vs 16-node r19)
// -> Y'_{i+1}.
__global__ __launch_bounds__(512) void k_agg_gemm(const uint4* __restrict__ H4,
                                                  const int* __restrict__ rowptr, const int* __restrict__ rowend,
                                                  const int* __restrict__ csr_src,
                                                  const float* __restrict__ dinv,
                                                  const float* __restrict__ bias, const float* __restrict__ gamma,
                                                  const float* __restrict__ beta,
                                                  const uint4* __restrict__ Bfr,
                                                  unsigned* __restrict__ Yn, int nnodes) {
    __shared__ ushort hs[32 * 136];
    int tid = threadIdx.x;
    int nl = tid >> 4;          // 0..31 node within block
    int l = tid & 15;
    int base = blockIdx.x * 32;

    // Phase A: aggregate one node per 16-lane group (same MLP as standalone)
    {
        int node = base + nl;
        int nodec = min(node, nnodes - 1);
        float acc[8], r[8];
        agg_body(H4, nodec, l, rowptr, rowend, csr_src, acc);
        bn_relu(acc, dinv[nodec], l, bias, gamma, beta, r);
        uint4 o;
        o.x = bf16rne(r[0]) | (bf16rne(r[1]) << 16);
        o.y = bf16rne(r[2]) | (bf16rne(r[3]) << 16);
        o.z = bf16rne(r[4]) | (bf16rne(r[5]) << 16);
        o.w = bf16rne(r[6]) | (bf16rne(r[7]) << 16);
        *(uint4*)&hs[nl * 136 + l * 8] = o;
    }
    __syncthreads();

    // Phase B: 32-row GEMM; wave w -> col tile w, 2 row tiles share B-frags.
    int w = tid >> 6, lane = tid & 63;
    bfrag a0[4], a1[4];
    #pragma unroll
    for (int kk = 0; kk < 4; kk++) {
        a0[kk] = *(const bfrag*)&hs[(lane & 15) * 136 + (lane >> 4) * 8 + kk * 32];
        a1[kk] = *(const bfrag*)&hs[(16 + (lane & 15)) * 136 + (lane >> 4) * 8 + kk * 32];
    }
    f32x4 ac0 = (f32x4){0.f, 0.f, 0.f, 0.f};
    f32x4 ac1 = (f32x4){0.f, 0.f, 0.f, 0.f};
    #pragma unroll
    for (int kk = 0; kk < 4; kk++) {
        bfrag bh = *(const bfrag*)&Bfr[(kk * 8 + w) * 64 + lane];
        bfrag bl = *(const bfrag*)&Bfr[2048 + (kk * 8 + w) * 64 + lane];
        ac0 = __builtin_amdgcn_mfma_f32_16x16x32_bf16(a0[kk], bh, ac0, 0, 0, 0);
        ac0 = __builtin_amdgcn_mfma_f32_16x16x32_bf16(a0[kk], bl, ac0, 0, 0, 0);
        ac1 = __builtin_amdgcn_mfma_f32_16x16x32_bf16(a1[kk], bh, ac1, 0, 0, 0);
        ac1 = __builtin_amdgcn_mfma_f32_16x16x32_bf16(a1[kk], bl, ac1, 0, 0, 0);
    }
    __syncthreads();   // all hs reads done; reuse hs for output
    #pragma unroll
    for (int r = 0; r < 4; r++) {
        int rowt = (lane >> 4) * 4 + r;
        float dv0 = dinv[min(base + rowt, nnodes - 1)];
        float dv1 = dinv[min(base + 16 + rowt, nnodes - 1)];
        hs[rowt * 136 + w * 16 + (lane & 15)] = (ushort)bf16rne(ac0[r] * dv0);
        hs[(16 + rowt) * 136 + w * 16 + (lane & 15)] = (ushort)bf16rne(ac1[r] * dv1);
    }
    __syncthreads();
    {
        int row = tid >> 4, q = tid & 15;
        int grow = base + row;
        if (grow < nnodes)
            ((uint4*)Yn)[(size_t)grow * 16 + q] = *(const uint4*)&hs[row * 136 + q * 8];
    }
}

// FUSED final layer: aggregate (16 nodes/block) + BN/ReLU -> fp32 in LDS ->
// run-compressed pooling atomics (h3 never materialized; k_pool deleted).
__global__ __launch_bounds__(256) void k_agg_pool(const uint4* __restrict__ H4, const int* __restrict__ rowptr,
                                                  const int* __restrict__ rowend,
                                                  const int* __restrict__ csr_src,
                                                  const float* __restrict__ dinv,
                                                  const float* __restrict__ bias, const float* __restrict__ gamma,
                                                  const float* __restrict__ beta,
                                                  const int* __restrict__ batch,
                                                  float* __restrict__ pooled, float* __restrict__ cnt,
                                                  int nnodes) {
    __shared__ float hsf[16 * 132];
    __shared__ int bg[16];
    int tid = threadIdx.x;
    int nl = tid >> 4;
    int l = tid & 15;
    int base = blockIdx.x * 16;
    int nn = min(16, nnodes - base);

    if (tid < 16) bg[tid] = batch[min(base + tid, nnodes - 1)];

    // Phase A: aggregate one node per 16-lane group
    {
        int node = base + nl;
        int nodec = min(node, nnodes - 1);
        float acc[8], r[8];
        agg_body(H4, nodec, l, rowptr, rowend, csr_src, acc);
        bn_relu(acc, dinv[nodec], l, bias, gamma, beta, r);
        #pragma unroll
        for (int i = 0; i < 8; i++) hsf[nl * 132 + l * 8 + i] = r[i];
    }
    __syncthreads();

    // Phase B: run-compressed pooling. threads 0..127 own one column each;
    // thread 128 accumulates per-graph node counts.
    if (tid < 128) {
        float ax = 0.f;
        int curg = bg[0];
        for (int i = 0; i < nn; i++) {
            int g = bg[i];
            if (g != curg) {
                atomicAdd(&pooled[(size_t)curg * 128 + tid], ax);
                ax = 0.f; curg = g;
            }
            ax += hsf[i * 132 + tid];
        }
        if (nn > 0) atomicAdd(&pooled[(size_t)curg * 128 + tid], ax);
    } else if (tid == 128) {
        float run = 0.f;
        int curg = bg[0];
        for (int i = 0; i < nn; i++) {
            int g = bg[i];
            if (g != curg) {
                atomicAdd(&cnt[curg], run);
                run = 0.f; curg = g;
            }
            run += 1.f;
        }
        if (nn > 0) atomicAdd(&cnt[curg], run);
    }
}

// classifier: one 64-thread block per graph. 128 -> 64 (relu) -> 10
__global__ __launch_bounds__(64) void k_classifier(const float* __restrict__ pooled, const float* __restrict__ cnt,
                                                   const float* __restrict__ Wc1, const float* __restrict__ bc1,
                                                   const float* __restrict__ Wc2, const float* __restrict__ bc2,
                                                   float* __restrict__ outp, int ngraphs) {
    __shared__ float p[128];
    __shared__ float z[64];
    int g = blockIdx.x;
    int tid = threadIdx.x;
    float inv = 1.0f / fmaxf(cnt[g], 1.0f);
    p[tid]      = pooled[(size_t)g * 128 + tid] * inv;
    p[tid + 64] = pooled[(size_t)g * 128 + 64 + tid] * inv;
    __syncthreads();
    float a = bc1[tid];
    #pragma unroll 8
    for (int k = 0; k < 128; k++) a += p[k] * Wc1[k * 64 + tid];
    z[tid] = fmaxf(a, 0.f);
    __syncthreads();
    if (tid < 10) {
        float o = bc2[tid];
        #pragma unroll 8
        for (int j = 0; j < 64; j++) o += z[j] * Wc2[j * 10 + tid];
        outp[(size_t)g * 10 + tid] = o;
    }
}

// ---------------- launch ----------------

static inline size_t align16(size_t v) { return (v + 15) & ~(size_t)15; }

extern "C" void kernel_launch(void* const* d_in, const int* in_sizes, int n_in,
                              void* d_out, int out_size, void* d_ws, size_t ws_size,
                              hipStream_t stream) {
    const float* x      = (const float*)d_in[0];
    const int*   ei     = (const int*)d_in[1];
    const int*   batch  = (const int*)d_in[2];
    const float* W1 = (const float*)d_in[3];  const float* b1 = (const float*)d_in[4];
    const float* W2 = (const float*)d_in[5];  const float* b2 = (const float*)d_in[6];
    const float* W3 = (const float*)d_in[7];  const float* b3 = (const float*)d_in[8];
    const float* g1 = (const float*)d_in[9];  const float* be1 = (const float*)d_in[10];
    const float* g2 = (const float*)d_in[11]; const float* be2 = (const float*)d_in[12];
    const float* g3 = (const float*)d_in[13]; const float* be3 = (const float*)d_in[14];
    const float* Wc1 = (const float*)d_in[15]; const float* bc1 = (const float*)d_in[16];
    const float* Wc2 = (const float*)d_in[17]; const float* bc2 = (const float*)d_in[18];

    const int N = in_sizes[0] / 128;
    const int E = in_sizes[1] / 2;
    const int G = out_size / 10;
    const int* srcp = ei;
    const int* dstp = ei + E;
    const int NB = (N + 511) >> 9;   // dst buckets of 512 nodes

    // workspace layout (16B-aligned slots); bufA/bufB have +1 zero dummy row
    char* ws = (char*)d_ws;
    size_t off = 0;
    unsigned* bufA = (unsigned*)(ws + off); off = align16(off + (size_t)(N + 1) * 64 * 4);
    unsigned* bufB = (unsigned*)(ws + off); off = align16(off + (size_t)(N + 1) * 64 * 4);
    uint4* Bfr1 = (uint4*)(ws + off); off = align16(off + 4096 * 16);
    uint4* Bfr2 = (uint4*)(ws + off); off = align16(off + 4096 * 16);
    uint4* Bfr3 = (uint4*)(ws + off); off = align16(off + 4096 * 16);
    int*   csr_src = (int*)(ws + off);  off = align16(off + (size_t)NB * CSRCAP * 4);
    unsigned* binned = (unsigned*)(ws + off); off = align16(off + (size_t)NB * BCAP * 4);
    float* dinv   = (float*)(ws + off); off = align16(off + (size_t)N * 4);
    int*   rowptr = (int*)(ws + off);   off = align16(off + (size_t)N * 4);
    int*   rowend = (int*)(ws + off);   off = align16(off + (size_t)N * 4);
    int*   gcursor = (int*)(ws + off);  off = align16(off + 256 * 4);
    float* pooled = (float*)(ws + off); off = align16(off + (size_t)G * 128 * 4);
    float* cnt    = (float*)(ws + off); off = align16(off + (size_t)G * 4);
    (void)ws_size;

    int gE8 = (E + 8191) / 8192;

    // pooled/cnt zero (independent; front-loaded) + weight frags + cursor init
    hipMemsetAsync(pooled, 0, ((size_t)G * 128 + G) * 4, stream);
    k_prep<<<25, 256, 0, stream>>>(W1, W2, W3, Bfr1, Bfr2, Bfr3, gcursor, bufA, bufB, N);

    // graph structure: atomic-free CSR build (over-allocated buckets, padded rows)
    k_binA<<<gE8, 256, 0, stream>>>(srcp, dstp, gcursor, binned, E);
    k_binB2<<<NB, 256, 0, stream>>>(binned, gcursor, rowptr, rowend, dinv, csr_src, N, N);

    int gGemm = (N + 127) / 128;
    int gFuse = (N + 31) / 32;
    int gFin  = (N + 15) / 16;

    // layer 1 GEMM (fp32 input, in-register convert) -> Y1' (bufA)
    k_gemm_mfma_f32<<<gGemm, 512, 0, stream>>>(x, Bfr1, bufA, dinv, N);
    // fused layer 1 aggregate + layer 2 GEMM -> Y2' (bufB)
    k_agg_gemm<<<gFuse, 512, 0, stream>>>((const uint4*)bufA, rowptr, rowend, csr_src, dinv,
                                          b1, g1, be1, Bfr2, bufB, N);
    // fused layer 2 aggregate + layer 3 GEMM -> Y3' (bufA)
    k_agg_gemm<<<gFuse, 512, 0, stream>>>((const uint4*)bufB, rowptr, rowend, csr_src, dinv,
                                          b2, g2, be2, Bfr3, bufA, N);
    // fused final aggregate + pooling (h3 never materialized)
    k_agg_pool<<<gFin, 256, 0, stream>>>((const uint4*)bufA, rowptr, rowend, csr_src, dinv,
                                         b3, g3, be3, batch, pooled, cnt, N);

    // classifier
    k_classifier<<<G, 64, 0, stream>>>(pooled, cnt, Wc1, bc1, Wc2, bc2, (float*)d_out, G);
}